// Round 11
// baseline (3544.294 us; speedup 1.0000x reference)
//
#include <hip/hip_runtime.h>
#include <hip/hip_bf16.h>

#define TL 2048
#define NB 64
#define NH 64
#define NLAY 10
#define NRESU 3
#define RSTEP 64

typedef float f32x4 __attribute__((ext_vector_type(4)));
typedef unsigned u32x2 __attribute__((ext_vector_type(2)));
typedef unsigned u32x4 __attribute__((ext_vector_type(4)));
typedef short bhalf8 __attribute__((ext_vector_type(8)));
typedef short bhalf4 __attribute__((ext_vector_type(4)));

__device__ __forceinline__ unsigned short f2bf(float f) {
    unsigned u = __float_as_uint(f);
    unsigned r = u + 0x7fffu + ((u >> 16) & 1u);
    return (unsigned short)(r >> 16);
}
__device__ __forceinline__ float bf2f(unsigned short h) {
    return __uint_as_float(((unsigned)h) << 16);
}
__device__ __forceinline__ float fast_sigmoid(float x) {
    return __builtin_amdgcn_rcpf(1.0f + __expf(-x));
}
__device__ __forceinline__ float fast_tanh(float x) {
    float e = __expf(2.0f * x);
    return 1.0f - 2.0f * __builtin_amdgcn_rcpf(e + 1.0f);
}

// ---------------- frontend ----------------
__global__ __launch_bounds__(256) void k_frontend(
    const float* __restrict__ in,
    const float* __restrict__ c1w, const float* __restrict__ c1b,
    const float* __restrict__ c2w, const float* __restrict__ c2b,
    float* __restrict__ x0)
{
    __shared__ float s_c1w[128];
    __shared__ float s_c1b[32];
    __shared__ float s_c2w[64 * 33];
    __shared__ float s_c2b[64];
    __shared__ float h1[64 * 33];
    __shared__ float ot[64 * 65];
    int tid = threadIdx.x;
    int b = blockIdx.x >> 5;
    int l0 = (blockIdx.x & 31) << 6;
    if (tid < 128) s_c1w[tid] = c1w[tid];
    if (tid < 32) s_c1b[tid] = c1b[tid];
    if (tid < 64) s_c2b[tid] = c2b[tid];
    for (int r = tid; r < 2048; r += 256) s_c2w[(r >> 5) * 33 + (r & 31)] = c2w[r];
    __syncthreads();
    if (tid < 64) {
        const float* ip = in + ((size_t)b * TL + l0 + tid) * 4;
        float x0v = ip[0], x1 = ip[1], x2 = ip[2], x3 = ip[3];
#pragma unroll
        for (int o = 0; o < 32; o++) {
            float a = s_c1w[o * 4 + 0] * x0v + s_c1w[o * 4 + 1] * x1 +
                      s_c1w[o * 4 + 2] * x2 + s_c1w[o * 4 + 3] * x3 + s_c1b[o];
            h1[tid * 33 + o] = fmaxf(a, 0.0f);
        }
    }
    __syncthreads();
    {
        int o = tid & 63, lg = tid >> 6;
#pragma unroll
        for (int j = 0; j < 16; j++) {
            int l = lg * 16 + j;
            float a = s_c2b[o];
#pragma unroll
            for (int i = 0; i < 32; i++) a += h1[l * 33 + i] * s_c2w[o * 33 + i];
            ot[o * 65 + l] = fmaxf(a, 0.0f);
        }
    }
    __syncthreads();
    for (int r = 0; r < 16; r++) {
        int idx = tid + 256 * r;
        int c = idx >> 6, l = idx & 63;
        x0[((size_t)b * 64 + c) * TL + l0 + l] = ot[c * 65 + l];
    }
}

// ---------------- weight transpose for resconv ----------------
__global__ __launch_bounds__(256) void k_prepw(const float* __restrict__ w, float* __restrict__ wt)
{
    int idx = blockIdx.x * 256 + threadIdx.x;
    if (idx >= NRESU * 64 * 64 * 11) return;
    int k = idx % 11;
    int rest = idx / 11;
    int i = rest & 63;
    int o = (rest >> 6) & 63;
    int uu = rest >> 12;
    wt[(((size_t)uu * 64 + i) * 11 + k) * 64 + o] = w[idx];
}

// ---------------- residual conv k=11 pad=5 ----------------
__global__ __launch_bounds__(256) void k_resconv(
    const float* __restrict__ in, float* __restrict__ out,
    const float* __restrict__ wt, const float* __restrict__ bias,
    const float* __restrict__ bg, const float* __restrict__ bb,
    const float* __restrict__ bm, const float* __restrict__ bv,
    int accumulate)
{
    __shared__ float sscale[64], sshift[64];
    __shared__ float ht[64 * 139];
    int tid = threadIdx.x;
    int b = blockIdx.x >> 4;
    int l0 = (blockIdx.x & 15) << 7;
    if (tid < 64) {
        float sc = bg[tid] * rsqrtf(bv[tid] + 1e-5f);
        sscale[tid] = sc;
        sshift[tid] = bb[tid] - bm[tid] * sc;
    }
    __syncthreads();
    for (int r = 0; r < 35; r++) {
        int idx = tid + 256 * r;
        if (idx < 64 * 138) {
            int i = idx / 138, ll = idx - i * 138;
            int l = l0 - 5 + ll;
            float v = 0.0f;
            if (l >= 0 && l < TL) v = in[((size_t)b * 64 + i) * TL + l];
            ht[i * 139 + ll] = fmaxf(v * sscale[i] + sshift[i], 0.0f);
        }
    }
    __syncthreads();
    int o = tid & 63, lq = tid >> 6;
    float acc[32];
#pragma unroll
    for (int j = 0; j < 32; j++) acc[j] = 0.0f;
    for (int i = 0; i < 64; i++) {
        float wr[11];
#pragma unroll
        for (int k = 0; k < 11; k++) wr[k] = wt[(i * 11 + k) * 64 + o];
        float hr[42];
        const float* hp = ht + i * 139 + lq * 32;
#pragma unroll
        for (int k = 0; k < 42; k++) hr[k] = hp[k];
#pragma unroll
        for (int k = 0; k < 11; k++)
#pragma unroll
            for (int j = 0; j < 32; j++) acc[j] += hr[k + j] * wr[k];
    }
    float bsv = bias[o];
    float* op = out + ((size_t)b * 64 + o) * TL + l0 + lq * 32;
    if (accumulate) {
#pragma unroll
        for (int j = 0; j < 32; j++) op[j] += acc[j] + bsv;
    } else {
#pragma unroll
        for (int j = 0; j < 32; j++) op[j] = acc[j] + bsv;
    }
}

// ---------------- transpose+cast: [NB][64][TL] f32 -> [TL][NB*64] bf16 ----------------
__global__ __launch_bounds__(256) void k_transpose(
    const float* __restrict__ x0, unsigned short* __restrict__ Xbf)
{
    __shared__ float t[64 * 65];
    int tid = threadIdx.x;
    int b = blockIdx.x >> 5;
    int t0 = (blockIdx.x & 31) << 6;
    for (int r = 0; r < 16; r++) {
        int idx = tid + 256 * r;
        int c = idx >> 6, tt = idx & 63;
        t[c * 65 + tt] = x0[((size_t)b * 64 + c) * TL + t0 + tt];
    }
    __syncthreads();
    for (int r = 0; r < 16; r++) {
        int idx = tid + 256 * r;
        int tt = idx >> 6, c = idx & 63;
        Xbf[((size_t)(t0 + tt)) * (NB * NH) + b * 64 + c] = f2bf(t[c * 65 + tt]);
    }
}

// ---------------- pipelined 10-layer LSTM: bf16, 512 thr = 2 groups, SLACKED protocol ----------------
// Identical to round-10 except handshake constants:
//   prologue skew 16 -> 32 published (actual offset 40 = 5 supersteps)
//   backpressure   48 -> 64 (ring-64 exact safety bound)
// -> both forward and backward polls have >=2-superstep slack; agent-scope flag
// propagation latency leaves the critical path (was paid once per 8 steps, zero-slack).
__global__ __launch_bounds__(512) void k_lstm(
    const unsigned short* __restrict__ Xbf,
    const float* __restrict__ w_ih, const float* __restrict__ w_hh,
    const float* __restrict__ b_ih, const float* __restrict__ b_hh,
    unsigned short* __restrict__ ring, float* __restrict__ final_h, int* prog)
{
    int bid = blockIdx.x;             // 0..19
    int layer = bid >> 1;
    int pair = bid & 1;
    int tid = threadIdx.x;
    int g2 = tid >> 8;
    int tg = tid & 255;
    int wv = tg >> 6;
    int lane = tid & 63;
    int l15 = lane & 15, l4 = lane >> 4;
    int u = wv * 16 + l15;
    int gidx = pair * 2 + g2;
    int b0 = gidx * 16;
    int self = layer * 4 + gidx;
    const bool has_store = (layer < NLAY - 1);
    const bool use_ring = (layer > 0);
    int brow = tg >> 4;
    int cc0 = (tg * 4) & 63;

    __shared__ __align__(16) unsigned short XH[2][2][16][136];  // [g2][buf][b][x(64)|h(64)]

    // ---- weights (bf16) into registers ----
    bhalf8 Bh[4][4];
    float bias_v[4];
#pragma unroll
    for (int nt = 0; nt < 4; nt++) {
        int n = (nt * 4 + wv) * 16 + l15;
        const float* rih = w_ih + ((size_t)layer * 256 + n) * 64;
        const float* rhh = w_hh + ((size_t)layer * 256 + n) * 64;
        bias_v[nt] = b_ih[layer * 256 + n] + b_hh[layer * 256 + n];
#pragma unroll
        for (int kt = 0; kt < 4; kt++) {
#pragma unroll
            for (int j = 0; j < 8; j++) {
                int k = kt * 32 + l4 * 8 + j;
                float v = (k < 64) ? rih[k] : rhh[k - 64];
                Bh[nt][kt][j] = (short)f2bf(v);
            }
        }
    }
    for (int idx = tid; idx < 2 * 2 * 16 * 136; idx += 512) {
        ((unsigned short*)XH)[idx] = 0;
    }
    float cst[4] = {0.f, 0.f, 0.f, 0.f};

    int* p_self = prog + self * 32;
    int* p_prev = prog + (self - 4) * 32;
    int* p_next = prog + (self + 4) * 32;
    int cached_prev = 0, cached_next = 0;

#define POLL_GE(ptr, tgt, cachev)                                                     \
    if (cachev < (tgt)) {                                                             \
        int v_; long g_ = 0;                                                          \
        while ((v_ = __hip_atomic_load(ptr, __ATOMIC_ACQUIRE,                         \
                        __HIP_MEMORY_SCOPE_AGENT)) < (tgt) && ++g_ < 1500000)         \
            __builtin_amdgcn_s_sleep(2);                                              \
        cachev = v_;                                                                  \
    }

    // ---- prologue: wait prev published>=32 (actual 40 = 5 supersteps of slack) ----
    if (tg == 0 && layer > 0) { POLL_GE(p_prev, 32, cached_prev); }
    __syncthreads();
    u32x2 px[4];
    {
        u32x2 p0;
        if (!use_ring) {
            const unsigned short* s0 = Xbf + (size_t)(b0 + brow) * 64 + cc0;
            asm volatile("global_load_dwordx2 %0, %1, off" : "=&v"(p0) : "v"(s0) : "memory");
        } else {
            const unsigned short* s0 = ring + ((size_t)(layer - 1) * RSTEP) * 4096 + (b0 + brow) * 64 + cc0;
            asm volatile("global_load_dwordx2 %0, %1, off sc0 sc1" : "=&v"(p0) : "v"(s0) : "memory");
        }
        asm volatile("s_waitcnt vmcnt(0)" ::: "memory");
        __builtin_amdgcn_sched_barrier(0);
        *(u32x2*)&XH[g2][0][brow][cc0] = p0;
#pragma unroll
        for (int pre = 1; pre <= 3; pre++) {
            if (!use_ring) {
                const unsigned short* sp = Xbf + ((size_t)pre * NB + b0 + brow) * 64 + cc0;
                asm volatile("global_load_dwordx2 %0, %1, off" : "=&v"(px[pre]) : "v"(sp) : "memory");
            } else {
                const unsigned short* sp = ring + ((size_t)(layer - 1) * RSTEP + pre) * 4096 + (b0 + brow) * 64 + cc0;
                asm volatile("global_load_dwordx2 %0, %1, off sc0 sc1" : "=&v"(px[pre]) : "v"(sp) : "memory");
            }
        }
    }
    asm volatile("s_waitcnt vmcnt(0)" ::: "memory");
    __builtin_amdgcn_sched_barrier(0);
    __syncthreads();

    for (int t0 = 0; t0 < TL; t0 += 8) {
#pragma unroll
        for (int ts = 0; ts < 8; ++ts) {
            const int p = ts & 1, q = p ^ 1;
            const int t = t0 + ts;
            const int cons = (ts + 1) & 3;   // px slot holding x(t+1)
            const int pref = ts & 3;         // slot to refill with x(t+4)

            // ---- gates = Xcat @ Wcat^T (bf16, fp32 accum), 4 chains, bias in init ----
            f32x4 A0 = {bias_v[0], bias_v[0], bias_v[0], bias_v[0]};
            f32x4 A1 = {bias_v[1], bias_v[1], bias_v[1], bias_v[1]};
            f32x4 A2 = {bias_v[2], bias_v[2], bias_v[2], bias_v[2]};
            f32x4 A3 = {bias_v[3], bias_v[3], bias_v[3], bias_v[3]};
#pragma unroll
            for (int kt = 0; kt < 4; kt++) {
                bhalf8 Ah = *(const bhalf8*)&XH[g2][p][l15][kt * 32 + l4 * 8];
                A0 = __builtin_amdgcn_mfma_f32_16x16x32_bf16(Ah, Bh[0][kt], A0, 0, 0, 0);
                A1 = __builtin_amdgcn_mfma_f32_16x16x32_bf16(Ah, Bh[1][kt], A1, 0, 0, 0);
                A2 = __builtin_amdgcn_mfma_f32_16x16x32_bf16(Ah, Bh[2][kt], A2, 0, 0, 0);
                A3 = __builtin_amdgcn_mfma_f32_16x16x32_bf16(Ah, Bh[3][kt], A3, 0, 0, 0);
            }

            // ---- lane-local nonlinearity (fp32) ----
            float hv4[4];
            unsigned short hb4[4];
#pragma unroll
            for (int r = 0; r < 4; r++) {
                float c = fast_sigmoid(A1[r]) * cst[r] + fast_sigmoid(A0[r]) * fast_tanh(A2[r]);
                cst[r] = c;
                float h = fast_sigmoid(A3[r]) * fast_tanh(c);
                hv4[r] = h;
                hb4[r] = f2bf(h);
            }

            // ---- counted wait for x(t+1) only (loaded 3 steps ago) ----
            if (has_store) { asm volatile("s_waitcnt vmcnt(10)" ::: "memory"); }
            else           { asm volatile("s_waitcnt vmcnt(2)" ::: "memory"); }
            __builtin_amdgcn_sched_barrier(0);

            // ---- stage x(t+1) into buf q (raw 8B copy, no VALU) ----
            *(u32x2*)&XH[g2][q][brow][cc0] = px[cons];

            // ---- own h into buf q; fire-and-forget ring stores (ushort) ----
#pragma unroll
            for (int r = 0; r < 4; r++) {
                XH[g2][q][l4 * 4 + r][64 + u] = hb4[r];
            }
            if (has_store) {
                unsigned short* dst = ring + ((size_t)layer * RSTEP + (t & 63)) * 4096;
#pragma unroll
                for (int r = 0; r < 4; r++) {
                    unsigned short* ap = dst + (b0 + l4 * 4 + r) * 64 + u;
                    unsigned val = hb4[r];
                    asm volatile("global_store_short %0, %1, off sc0 sc1" :: "v"(ap), "v"(val) : "memory");
                }
            } else if (t == TL - 1) {
#pragma unroll
                for (int r = 0; r < 4; r++)
                    final_h[(b0 + l4 * 4 + r) * NH + u] = hv4[r];
            }

            // ---- prefetch x(t+4) ----
            {
                int tt = t + 4; if (tt > TL - 1) tt = TL - 1;
                if (!use_ring) {
                    const unsigned short* sp = Xbf + ((size_t)tt * NB + b0 + brow) * 64 + cc0;
                    asm volatile("global_load_dwordx2 %0, %1, off" : "=&v"(px[pref]) : "v"(sp) : "memory");
                } else {
                    const unsigned short* sp = ring + ((size_t)(layer - 1) * RSTEP + (tt & 63)) * 4096 + (b0 + brow) * 64 + cc0;
                    asm volatile("global_load_dwordx2 %0, %1, off sc0 sc1" : "=&v"(px[pref]) : "v"(sp) : "memory");
                }
            }

            asm volatile("s_waitcnt lgkmcnt(0)" ::: "memory");
            __builtin_amdgcn_s_barrier();
            __builtin_amdgcn_sched_barrier(0);
        }

        // ---- superstep end: counted drain, publish, slack-fixed polls ----
        if (has_store) { asm volatile("s_waitcnt vmcnt(40)" ::: "memory"); }
        __builtin_amdgcn_s_barrier();
        __builtin_amdgcn_sched_barrier(0);
        if (tg == 0) {
            __hip_atomic_store(p_self, t0, __ATOMIC_RELEASE, __HIP_MEMORY_SCOPE_AGENT);
            int nt0 = t0 + 8;
            if (nt0 < TL) {
                if (use_ring) {
                    int tgt = nt0 + 16; if (tgt > TL) tgt = TL;
                    POLL_GE(p_prev, tgt, cached_prev);
                }
                if (has_store) {
                    int need = nt0 - 64;   // exact ring-64 safety bound (was -48: zero-slack)
                    if (need > 0) { POLL_GE(p_next, need, cached_next); }
                }
            }
        }
        __builtin_amdgcn_s_barrier();
        __builtin_amdgcn_sched_barrier(0);
    }

    // ---- epilogue: full drain, final publish ----
    asm volatile("s_waitcnt vmcnt(0)" ::: "memory");
    __builtin_amdgcn_s_barrier();
    if (tg == 0) {
        __hip_atomic_store(p_self, TL, __ATOMIC_RELEASE, __HIP_MEMORY_SCOPE_AGENT);
    }
#undef POLL_GE
}

// ---------------- head ----------------
__global__ void k_head(const float* __restrict__ fh, const float* __restrict__ ow,
                       const float* __restrict__ ob, float* __restrict__ out)
{
    int b = threadIdx.x;
    if (b >= NB) return;
    const float* h = fh + b * NH;
    float l0 = ob[0], l1 = ob[1];
    for (int uu = 0; uu < 64; uu++) { l0 += h[uu] * ow[uu * 2]; l1 += h[uu] * ow[uu * 2 + 1]; }
    float m = fmaxf(l0, l1);
    float s = expf(l0 - m) + expf(l1 - m);
    float ls = m + logf(s);
    out[b * 2] = l0 - ls;
    out[b * 2 + 1] = l1 - ls;
}

extern "C" void kernel_launch(void* const* d_in, const int* in_sizes, int n_in,
                              void* d_out, int out_size, void* d_ws, size_t ws_size,
                              hipStream_t stream) {
    const float* input = (const float*)d_in[0];
    const float* c1w = (const float*)d_in[2];
    const float* c1b = (const float*)d_in[3];
    const float* c2w = (const float*)d_in[4];
    const float* c2b = (const float*)d_in[5];
    const float* bn1g = (const float*)d_in[6];
    const float* bn1b = (const float*)d_in[7];
    const float* bn1m = (const float*)d_in[8];
    const float* bn1v = (const float*)d_in[9];
    const float* rw1 = (const float*)d_in[10];
    const float* rb1 = (const float*)d_in[11];
    const float* bn2g = (const float*)d_in[12];
    const float* bn2b = (const float*)d_in[13];
    const float* bn2m = (const float*)d_in[14];
    const float* bn2v = (const float*)d_in[15];
    const float* rw2 = (const float*)d_in[16];
    const float* rb2 = (const float*)d_in[17];
    const float* wih = (const float*)d_in[18];
    const float* whh = (const float*)d_in[19];
    const float* bih = (const float*)d_in[20];
    const float* bhh = (const float*)d_in[21];
    const float* outw = (const float*)d_in[22];
    const float* outb = (const float*)d_in[23];

    float* ws = (float*)d_ws;
    float*          x0buf = ws;                              // [NB][64][TL] f32
    float*          t1buf = x0buf + 8388608;                 // [NB][64][TL] f32
    unsigned short* Xbf   = (unsigned short*)(t1buf + 8388608);  // [TL][NB*64] bf16
    unsigned short* ringb = Xbf + 8388608;                   // [9][64][64b][64u] bf16
    float*          fhbuf = (float*)(ringb + 2359296);       // [NB][NH]
    int*            progb = (int*)(fhbuf + 4096);            // 40 flags x 32
    float*          wt1   = (float*)(progb + 40 * 32);
    float*          wt2   = wt1 + NRESU * 64 * 64 * 11;

    hipMemsetAsync(progb, 0, 40 * 32 * sizeof(int), stream);

    k_prepw<<<528, 256, 0, stream>>>(rw1, wt1);
    k_prepw<<<528, 256, 0, stream>>>(rw2, wt2);
    k_frontend<<<2048, 256, 0, stream>>>(input, c1w, c1b, c2w, c2b, x0buf);
    for (int uu = 0; uu < NRESU; uu++) {
        k_resconv<<<1024, 256, 0, stream>>>(x0buf, t1buf, wt1 + uu * 45056, rb1 + uu * 64,
                                            bn1g + uu * 64, bn1b + uu * 64, bn1m + uu * 64, bn1v + uu * 64, 0);
        k_resconv<<<1024, 256, 0, stream>>>(t1buf, x0buf, wt2 + uu * 45056, rb2 + uu * 64,
                                            bn2g + uu * 64, bn2b + uu * 64, bn2m + uu * 64, bn2v + uu * 64, 1);
    }
    k_transpose<<<2048, 256, 0, stream>>>(x0buf, Xbf);
    k_lstm<<<20, 512, 0, stream>>>(Xbf, wih, whh, bih, bhh, ringb, fhbuf, progb);
    k_head<<<1, 64, 0, stream>>>(fhbuf, outw, outb, (float*)d_out);
}

// Round 12
// 3088.576 us; speedup vs baseline: 1.1475x; 1.1475x over previous
//
#include <hip/hip_runtime.h>
#include <hip/hip_bf16.h>

#define TL 2048
#define NB 64
#define NH 64
#define NLAY 10
#define NRESU 3
#define RSTEP 64

typedef float f32x4 __attribute__((ext_vector_type(4)));
typedef unsigned u32x2 __attribute__((ext_vector_type(2)));
typedef short bhalf8 __attribute__((ext_vector_type(8)));

__device__ __forceinline__ unsigned short f2bf(float f) {
    unsigned u = __float_as_uint(f);
    unsigned r = u + 0x7fffu + ((u >> 16) & 1u);
    return (unsigned short)(r >> 16);
}
__device__ __forceinline__ float bf2f(unsigned short h) {
    return __uint_as_float(((unsigned)h) << 16);
}
__device__ __forceinline__ float fast_sigmoid(float x) {
    return __builtin_amdgcn_rcpf(1.0f + __expf(-x));
}
__device__ __forceinline__ float fast_tanh(float x) {
    float e = __expf(2.0f * x);
    return 1.0f - 2.0f * __builtin_amdgcn_rcpf(e + 1.0f);
}

// ---------------- frontend ----------------
__global__ __launch_bounds__(256) void k_frontend(
    const float* __restrict__ in,
    const float* __restrict__ c1w, const float* __restrict__ c1b,
    const float* __restrict__ c2w, const float* __restrict__ c2b,
    float* __restrict__ x0)
{
    __shared__ float s_c1w[128];
    __shared__ float s_c1b[32];
    __shared__ float s_c2w[64 * 33];
    __shared__ float s_c2b[64];
    __shared__ float h1[64 * 33];
    __shared__ float ot[64 * 65];
    int tid = threadIdx.x;
    int b = blockIdx.x >> 5;
    int l0 = (blockIdx.x & 31) << 6;
    if (tid < 128) s_c1w[tid] = c1w[tid];
    if (tid < 32) s_c1b[tid] = c1b[tid];
    if (tid < 64) s_c2b[tid] = c2b[tid];
    for (int r = tid; r < 2048; r += 256) s_c2w[(r >> 5) * 33 + (r & 31)] = c2w[r];
    __syncthreads();
    if (tid < 64) {
        const float* ip = in + ((size_t)b * TL + l0 + tid) * 4;
        float x0v = ip[0], x1 = ip[1], x2 = ip[2], x3 = ip[3];
#pragma unroll
        for (int o = 0; o < 32; o++) {
            float a = s_c1w[o * 4 + 0] * x0v + s_c1w[o * 4 + 1] * x1 +
                      s_c1w[o * 4 + 2] * x2 + s_c1w[o * 4 + 3] * x3 + s_c1b[o];
            h1[tid * 33 + o] = fmaxf(a, 0.0f);
        }
    }
    __syncthreads();
    {
        int o = tid & 63, lg = tid >> 6;
#pragma unroll
        for (int j = 0; j < 16; j++) {
            int l = lg * 16 + j;
            float a = s_c2b[o];
#pragma unroll
            for (int i = 0; i < 32; i++) a += h1[l * 33 + i] * s_c2w[o * 33 + i];
            ot[o * 65 + l] = fmaxf(a, 0.0f);
        }
    }
    __syncthreads();
    for (int r = 0; r < 16; r++) {
        int idx = tid + 256 * r;
        int c = idx >> 6, l = idx & 63;
        x0[((size_t)b * 64 + c) * TL + l0 + l] = ot[c * 65 + l];
    }
}

// ---------------- weight transpose for resconv ----------------
__global__ __launch_bounds__(256) void k_prepw(const float* __restrict__ w, float* __restrict__ wt)
{
    int idx = blockIdx.x * 256 + threadIdx.x;
    if (idx >= NRESU * 64 * 64 * 11) return;
    int k = idx % 11;
    int rest = idx / 11;
    int i = rest & 63;
    int o = (rest >> 6) & 63;
    int uu = rest >> 12;
    wt[(((size_t)uu * 64 + i) * 11 + k) * 64 + o] = w[idx];
}

// ---------------- residual conv k=11 pad=5 ----------------
__global__ __launch_bounds__(256) void k_resconv(
    const float* __restrict__ in, float* __restrict__ out,
    const float* __restrict__ wt, const float* __restrict__ bias,
    const float* __restrict__ bg, const float* __restrict__ bb,
    const float* __restrict__ bm, const float* __restrict__ bv,
    int accumulate)
{
    __shared__ float sscale[64], sshift[64];
    __shared__ float ht[64 * 139];
    int tid = threadIdx.x;
    int b = blockIdx.x >> 4;
    int l0 = (blockIdx.x & 15) << 7;
    if (tid < 64) {
        float sc = bg[tid] * rsqrtf(bv[tid] + 1e-5f);
        sscale[tid] = sc;
        sshift[tid] = bb[tid] - bm[tid] * sc;
    }
    __syncthreads();
    for (int r = 0; r < 35; r++) {
        int idx = tid + 256 * r;
        if (idx < 64 * 138) {
            int i = idx / 138, ll = idx - i * 138;
            int l = l0 - 5 + ll;
            float v = 0.0f;
            if (l >= 0 && l < TL) v = in[((size_t)b * 64 + i) * TL + l];
            ht[i * 139 + ll] = fmaxf(v * sscale[i] + sshift[i], 0.0f);
        }
    }
    __syncthreads();
    int o = tid & 63, lq = tid >> 6;
    float acc[32];
#pragma unroll
    for (int j = 0; j < 32; j++) acc[j] = 0.0f;
    for (int i = 0; i < 64; i++) {
        float wr[11];
#pragma unroll
        for (int k = 0; k < 11; k++) wr[k] = wt[(i * 11 + k) * 64 + o];
        float hr[42];
        const float* hp = ht + i * 139 + lq * 32;
#pragma unroll
        for (int k = 0; k < 42; k++) hr[k] = hp[k];
#pragma unroll
        for (int k = 0; k < 11; k++)
#pragma unroll
            for (int j = 0; j < 32; j++) acc[j] += hr[k + j] * wr[k];
    }
    float bsv = bias[o];
    float* op = out + ((size_t)b * 64 + o) * TL + l0 + lq * 32;
    if (accumulate) {
#pragma unroll
        for (int j = 0; j < 32; j++) op[j] += acc[j] + bsv;
    } else {
#pragma unroll
        for (int j = 0; j < 32; j++) op[j] = acc[j] + bsv;
    }
}

// ---------------- transpose+cast: [NB][64][TL] f32 -> [TL][NB*64] bf16 ----------------
__global__ __launch_bounds__(256) void k_transpose(
    const float* __restrict__ x0, unsigned short* __restrict__ Xbf)
{
    __shared__ float t[64 * 65];
    int tid = threadIdx.x;
    int b = blockIdx.x >> 5;
    int t0 = (blockIdx.x & 31) << 6;
    for (int r = 0; r < 16; r++) {
        int idx = tid + 256 * r;
        int c = idx >> 6, tt = idx & 63;
        t[c * 65 + tt] = x0[((size_t)b * 64 + c) * TL + t0 + tt];
    }
    __syncthreads();
    for (int r = 0; r < 16; r++) {
        int idx = tid + 256 * r;
        int tt = idx >> 6, c = idx & 63;
        Xbf[((size_t)(t0 + tt)) * (NB * NH) + b * 64 + c] = f2bf(t[c * 65 + tt]);
    }
}

// ---------------- pipelined 10-layer LSTM: 1 group / 512-thr WG, gate-exchange ----------------
// 40 active WGs (layer x group). Per step: 64 MFMAs spread 8/wave (each wave owns 2
// n-tiles of 16 gates), gate values exchanged via LDS (f32, padded), nonlinearity
// redistributed 2 h-values/thread across all 512 threads -> per-wave trans work halved.
// Ring: 1 coalesced dword store + 1 dword load per thread; counted vmcnt(4)/(2);
// superstep drain vmcnt(1); round-11 slacked flag protocol verbatim.
__global__ __launch_bounds__(512) void k_lstm(
    const unsigned short* __restrict__ Xbf,
    const float* __restrict__ w_ih, const float* __restrict__ w_hh,
    const float* __restrict__ b_ih, const float* __restrict__ b_hh,
    unsigned short* __restrict__ ring, float* __restrict__ final_h, int* prog)
{
    int bid = blockIdx.x;             // 0..79; active: bid&7 < 4
    int grp = bid & 7;
    int layer = bid >> 3;
    if (grp >= 4 || layer >= NLAY) return;
    int b0 = grp * 16;
    int tid = threadIdx.x;
    int w = tid >> 6;                 // wave 0..7
    int lane = tid & 63;
    int l15 = lane & 15, l4 = lane >> 4;
    int self = layer * 4 + grp;
    const bool has_store = (layer < NLAY - 1);
    const bool use_ring = (layer > 0);
    int brow = tid >> 5;              // batch row 0..15
    int cc0 = (tid & 31) * 2;         // u pair base (even)
    int T0 = w * 2, T1 = w * 2 + 1;   // this wave's two n-tiles (of 16)

    __shared__ __align__(16) unsigned short XH[2][16][136];   // [buf][b][x(0..63)|h(64..127)]
    __shared__ float gbuf[16][16][17];                        // [tile][b][col] padded

    // ---- B-frags: 2 tiles x 4 kt (32 VGPRs) ----
    bhalf8 Bh[2][4];
#pragma unroll
    for (int s = 0; s < 2; s++) {
        int n = (w * 2 + s) * 16 + l15;
        const float* rih = w_ih + ((size_t)layer * 256 + n) * 64;
        const float* rhh = w_hh + ((size_t)layer * 256 + n) * 64;
#pragma unroll
        for (int kt = 0; kt < 4; kt++) {
#pragma unroll
            for (int j = 0; j < 8; j++) {
                int k = kt * 32 + l4 * 8 + j;
                float v = (k < 64) ? rih[k] : rhh[k - 64];
                Bh[s][kt][j] = (short)f2bf(v);
            }
        }
    }
    // ---- bias for this thread's 2 (u) values x 4 gates ----
    float bv[8];
#pragma unroll
    for (int g = 0; g < 4; g++) {
#pragma unroll
        for (int s = 0; s < 2; s++) {
            int n = g * 64 + cc0 + s;
            bv[g * 2 + s] = b_ih[layer * 256 + n] + b_hh[layer * 256 + n];
        }
    }
    // zero h regions (both buffers)
    for (int idx = tid; idx < 2 * 16 * 64; idx += 512) {
        XH[idx >> 10][(idx >> 6) & 15][64 + (idx & 63)] = 0;
    }
    float cst[2] = {0.f, 0.f};

    int* p_self = prog + self * 32;
    int* p_prev = prog + (self - 4) * 32;
    int* p_next = prog + (self + 4) * 32;
    int cached_prev = 0, cached_next = 0;

#define POLL_GE(ptr, tgt, cachev)                                                     \
    if (cachev < (tgt)) {                                                             \
        int v_; long g_ = 0;                                                          \
        while ((v_ = __hip_atomic_load(ptr, __ATOMIC_ACQUIRE,                         \
                        __HIP_MEMORY_SCOPE_AGENT)) < (tgt) && ++g_ < 1500000)         \
            __builtin_amdgcn_s_sleep(2);                                              \
        cachev = v_;                                                                  \
    }

    // ---- prologue: wait prev published>=32, stage x(0), preload x(1..3), drain ----
    if (tid == 0 && layer > 0) { POLL_GE(p_prev, 32, cached_prev); }
    __syncthreads();
    unsigned px[4];
    {
        unsigned p0;
        if (!use_ring) {
            const unsigned short* s0 = Xbf + (size_t)(b0 + brow) * 64 + cc0;
            asm volatile("global_load_dword %0, %1, off" : "=&v"(p0) : "v"(s0) : "memory");
        } else {
            const unsigned short* s0 = ring + ((size_t)(layer - 1) * RSTEP) * 4096 + (b0 + brow) * 64 + cc0;
            asm volatile("global_load_dword %0, %1, off sc0 sc1" : "=&v"(p0) : "v"(s0) : "memory");
        }
        asm volatile("s_waitcnt vmcnt(0)" ::: "memory");
        __builtin_amdgcn_sched_barrier(0);
        *(unsigned*)&XH[0][brow][cc0] = p0;
#pragma unroll
        for (int pre = 1; pre <= 3; pre++) {
            if (!use_ring) {
                const unsigned short* sp = Xbf + ((size_t)pre * NB + b0 + brow) * 64 + cc0;
                asm volatile("global_load_dword %0, %1, off" : "=&v"(px[pre]) : "v"(sp) : "memory");
            } else {
                const unsigned short* sp = ring + ((size_t)(layer - 1) * RSTEP + pre) * 4096 + (b0 + brow) * 64 + cc0;
                asm volatile("global_load_dword %0, %1, off sc0 sc1" : "=&v"(px[pre]) : "v"(sp) : "memory");
            }
        }
    }
    asm volatile("s_waitcnt vmcnt(0)" ::: "memory");
    __builtin_amdgcn_sched_barrier(0);
    __syncthreads();

    for (int t0 = 0; t0 < TL; t0 += 8) {
#pragma unroll
        for (int ts = 0; ts < 8; ++ts) {
            const int p = ts & 1, q = p ^ 1;
            const int t = t0 + ts;
            const int cons = (ts + 1) & 3;   // px slot holding x(t+1)
            const int pref = ts & 3;         // slot to refill with x(t+4)

            // ---- MFMA: this wave's 2 n-tiles over 4 kt (A-frags broadcast from LDS) ----
            f32x4 Acc0 = {0, 0, 0, 0}, Acc1 = {0, 0, 0, 0};
#pragma unroll
            for (int kt = 0; kt < 4; kt++) {
                bhalf8 Ah = *(const bhalf8*)&XH[p][l15][kt * 32 + l4 * 8];
                Acc0 = __builtin_amdgcn_mfma_f32_16x16x32_bf16(Ah, Bh[0][kt], Acc0, 0, 0, 0);
                Acc1 = __builtin_amdgcn_mfma_f32_16x16x32_bf16(Ah, Bh[1][kt], Acc1, 0, 0, 0);
            }
            // ---- gate exchange: write this wave's tiles to LDS ----
#pragma unroll
            for (int r = 0; r < 4; r++) {
                gbuf[T0][l4 * 4 + r][l15] = Acc0[r];
                gbuf[T1][l4 * 4 + r][l15] = Acc1[r];
            }
            asm volatile("s_waitcnt lgkmcnt(0)" ::: "memory");
            __builtin_amdgcn_s_barrier();
            __builtin_amdgcn_sched_barrier(0);

            // ---- counted wait for x(t+1) (issued step t-3) ----
            if (has_store) { asm volatile("s_waitcnt vmcnt(4)" ::: "memory"); }
            else           { asm volatile("s_waitcnt vmcnt(2)" ::: "memory"); }
            __builtin_amdgcn_sched_barrier(0);

            // ---- stage x(t+1) into buf q (1 dword, no VALU) ----
            *(unsigned*)&XH[q][brow][cc0] = px[cons];

            // ---- nonlinearity: 2 h-values for (brow, cc0), (brow, cc0+1) ----
            int tb = cc0 >> 4, cb = cc0 & 15;
            float hv[2];
#pragma unroll
            for (int s = 0; s < 2; s++) {
                float gi = gbuf[0 * 4 + tb][brow][cb + s] + bv[0 + s];
                float gf = gbuf[1 * 4 + tb][brow][cb + s] + bv[2 + s];
                float gg = gbuf[2 * 4 + tb][brow][cb + s] + bv[4 + s];
                float go = gbuf[3 * 4 + tb][brow][cb + s] + bv[6 + s];
                float c = fast_sigmoid(gf) * cst[s] + fast_sigmoid(gi) * fast_tanh(gg);
                cst[s] = c;
                hv[s] = fast_sigmoid(go) * fast_tanh(c);
            }
            unsigned hw = ((unsigned)f2bf(hv[1]) << 16) | (unsigned)f2bf(hv[0]);

            // ---- own h into buf q; coalesced ring store ----
            *(unsigned*)&XH[q][brow][64 + cc0] = hw;
            if (has_store) {
                unsigned short* ap = ring + ((size_t)layer * RSTEP + (t & 63)) * 4096 + (b0 + brow) * 64 + cc0;
                asm volatile("global_store_dword %0, %1, off sc0 sc1" :: "v"(ap), "v"(hw) : "memory");
            } else if (t == TL - 1) {
                final_h[(b0 + brow) * NH + cc0] = hv[0];
                final_h[(b0 + brow) * NH + cc0 + 1] = hv[1];
            }

            // ---- prefetch x(t+4) ----
            {
                int tt = t + 4; if (tt > TL - 1) tt = TL - 1;
                if (!use_ring) {
                    const unsigned short* sp = Xbf + ((size_t)tt * NB + b0 + brow) * 64 + cc0;
                    asm volatile("global_load_dword %0, %1, off" : "=&v"(px[pref]) : "v"(sp) : "memory");
                } else {
                    const unsigned short* sp = ring + ((size_t)(layer - 1) * RSTEP + (tt & 63)) * 4096 + (b0 + brow) * 64 + cc0;
                    asm volatile("global_load_dword %0, %1, off sc0 sc1" : "=&v"(px[pref]) : "v"(sp) : "memory");
                }
            }

            asm volatile("s_waitcnt lgkmcnt(0)" ::: "memory");
            __builtin_amdgcn_s_barrier();
            __builtin_amdgcn_sched_barrier(0);
        }

        // ---- superstep end: drain stores (vmcnt(1) = all but last load), publish, polls ----
        if (has_store) { asm volatile("s_waitcnt vmcnt(1)" ::: "memory"); }
        __builtin_amdgcn_s_barrier();
        __builtin_amdgcn_sched_barrier(0);
        if (tid == 0) {
            __hip_atomic_store(p_self, t0, __ATOMIC_RELEASE, __HIP_MEMORY_SCOPE_AGENT);
            int nt0 = t0 + 8;
            if (nt0 < TL) {
                if (use_ring) {
                    int tgt = nt0 + 16; if (tgt > TL) tgt = TL;
                    POLL_GE(p_prev, tgt, cached_prev);
                }
                if (has_store) {
                    int need = nt0 - 64;
                    if (need > 0) { POLL_GE(p_next, need, cached_next); }
                }
            }
        }
        __builtin_amdgcn_s_barrier();
        __builtin_amdgcn_sched_barrier(0);
    }

    // ---- epilogue: full drain, final publish ----
    asm volatile("s_waitcnt vmcnt(0)" ::: "memory");
    __builtin_amdgcn_s_barrier();
    if (tid == 0) {
        __hip_atomic_store(p_self, TL, __ATOMIC_RELEASE, __HIP_MEMORY_SCOPE_AGENT);
    }
#undef POLL_GE
}

// ---------------- head ----------------
__global__ void k_head(const float* __restrict__ fh, const float* __restrict__ ow,
                       const float* __restrict__ ob, float* __restrict__ out)
{
    int b = threadIdx.x;
    if (b >= NB) return;
    const float* h = fh + b * NH;
    float l0 = ob[0], l1 = ob[1];
    for (int uu = 0; uu < 64; uu++) { l0 += h[uu] * ow[uu * 2]; l1 += h[uu] * ow[uu * 2 + 1]; }
    float m = fmaxf(l0, l1);
    float s = expf(l0 - m) + expf(l1 - m);
    float ls = m + logf(s);
    out[b * 2] = l0 - ls;
    out[b * 2 + 1] = l1 - ls;
}

extern "C" void kernel_launch(void* const* d_in, const int* in_sizes, int n_in,
                              void* d_out, int out_size, void* d_ws, size_t ws_size,
                              hipStream_t stream) {
    const float* input = (const float*)d_in[0];
    const float* c1w = (const float*)d_in[2];
    const float* c1b = (const float*)d_in[3];
    const float* c2w = (const float*)d_in[4];
    const float* c2b = (const float*)d_in[5];
    const float* bn1g = (const float*)d_in[6];
    const float* bn1b = (const float*)d_in[7];
    const float* bn1m = (const float*)d_in[8];
    const float* bn1v = (const float*)d_in[9];
    const float* rw1 = (const float*)d_in[10];
    const float* rb1 = (const float*)d_in[11];
    const float* bn2g = (const float*)d_in[12];
    const float* bn2b = (const float*)d_in[13];
    const float* bn2m = (const float*)d_in[14];
    const float* bn2v = (const float*)d_in[15];
    const float* rw2 = (const float*)d_in[16];
    const float* rb2 = (const float*)d_in[17];
    const float* wih = (const float*)d_in[18];
    const float* whh = (const float*)d_in[19];
    const float* bih = (const float*)d_in[20];
    const float* bhh = (const float*)d_in[21];
    const float* outw = (const float*)d_in[22];
    const float* outb = (const float*)d_in[23];

    float* ws = (float*)d_ws;
    float*          x0buf = ws;                              // [NB][64][TL] f32
    float*          t1buf = x0buf + 8388608;                 // [NB][64][TL] f32
    unsigned short* Xbf   = (unsigned short*)(t1buf + 8388608);  // [TL][NB*64] bf16
    unsigned short* ringb = Xbf + 8388608;                   // [9][64][64b][64u] bf16
    float*          fhbuf = (float*)(ringb + 2359296);       // [NB][NH]
    int*            progb = (int*)(fhbuf + 4096);            // 40 flags x 32
    float*          wt1   = (float*)(progb + 40 * 32);
    float*          wt2   = wt1 + NRESU * 64 * 64 * 11;

    hipMemsetAsync(progb, 0, 40 * 32 * sizeof(int), stream);

    k_prepw<<<528, 256, 0, stream>>>(rw1, wt1);
    k_prepw<<<528, 256, 0, stream>>>(rw2, wt2);
    k_frontend<<<2048, 256, 0, stream>>>(input, c1w, c1b, c2w, c2b, x0buf);
    for (int uu = 0; uu < NRESU; uu++) {
        k_resconv<<<1024, 256, 0, stream>>>(x0buf, t1buf, wt1 + uu * 45056, rb1 + uu * 64,
                                            bn1g + uu * 64, bn1b + uu * 64, bn1m + uu * 64, bn1v + uu * 64, 0);
        k_resconv<<<1024, 256, 0, stream>>>(t1buf, x0buf, wt2 + uu * 45056, rb2 + uu * 64,
                                            bn2g + uu * 64, bn2b + uu * 64, bn2m + uu * 64, bn2v + uu * 64, 1);
    }
    k_transpose<<<2048, 256, 0, stream>>>(x0buf, Xbf);
    k_lstm<<<80, 512, 0, stream>>>(Xbf, wih, whh, bih, bhh, ringb, fhbuf, progb);
    k_head<<<1, 64, 0, stream>>>(fhbuf, outw, outb, (float*)d_out);
}

// Round 13
// 2831.921 us; speedup vs baseline: 1.2516x; 1.0906x over previous
//
#include <hip/hip_runtime.h>
#include <hip/hip_bf16.h>

#define TL 2048
#define NB 64
#define NH 64
#define NLAY 10
#define NRESU 3
#define RSTEP 64

typedef float f32x4 __attribute__((ext_vector_type(4)));
typedef unsigned u32x2 __attribute__((ext_vector_type(2)));
typedef short bhalf8 __attribute__((ext_vector_type(8)));

__device__ __forceinline__ unsigned short f2bf(float f) {
    unsigned u = __float_as_uint(f);
    unsigned r = u + 0x7fffu + ((u >> 16) & 1u);
    return (unsigned short)(r >> 16);
}
__device__ __forceinline__ float bf2f(unsigned short h) {
    return __uint_as_float(((unsigned)h) << 16);
}
__device__ __forceinline__ float fast_sigmoid(float x) {
    return __builtin_amdgcn_rcpf(1.0f + __expf(-x));
}
__device__ __forceinline__ float fast_tanh(float x) {
    float e = __expf(2.0f * x);
    return 1.0f - 2.0f * __builtin_amdgcn_rcpf(e + 1.0f);
}

// ---------------- frontend ----------------
__global__ __launch_bounds__(256) void k_frontend(
    const float* __restrict__ in,
    const float* __restrict__ c1w, const float* __restrict__ c1b,
    const float* __restrict__ c2w, const float* __restrict__ c2b,
    float* __restrict__ x0)
{
    __shared__ float s_c1w[128];
    __shared__ float s_c1b[32];
    __shared__ float s_c2w[64 * 33];
    __shared__ float s_c2b[64];
    __shared__ float h1[64 * 33];
    __shared__ float ot[64 * 65];
    int tid = threadIdx.x;
    int b = blockIdx.x >> 5;
    int l0 = (blockIdx.x & 31) << 6;
    if (tid < 128) s_c1w[tid] = c1w[tid];
    if (tid < 32) s_c1b[tid] = c1b[tid];
    if (tid < 64) s_c2b[tid] = c2b[tid];
    for (int r = tid; r < 2048; r += 256) s_c2w[(r >> 5) * 33 + (r & 31)] = c2w[r];
    __syncthreads();
    if (tid < 64) {
        const float* ip = in + ((size_t)b * TL + l0 + tid) * 4;
        float x0v = ip[0], x1 = ip[1], x2 = ip[2], x3 = ip[3];
#pragma unroll
        for (int o = 0; o < 32; o++) {
            float a = s_c1w[o * 4 + 0] * x0v + s_c1w[o * 4 + 1] * x1 +
                      s_c1w[o * 4 + 2] * x2 + s_c1w[o * 4 + 3] * x3 + s_c1b[o];
            h1[tid * 33 + o] = fmaxf(a, 0.0f);
        }
    }
    __syncthreads();
    {
        int o = tid & 63, lg = tid >> 6;
#pragma unroll
        for (int j = 0; j < 16; j++) {
            int l = lg * 16 + j;
            float a = s_c2b[o];
#pragma unroll
            for (int i = 0; i < 32; i++) a += h1[l * 33 + i] * s_c2w[o * 33 + i];
            ot[o * 65 + l] = fmaxf(a, 0.0f);
        }
    }
    __syncthreads();
    for (int r = 0; r < 16; r++) {
        int idx = tid + 256 * r;
        int c = idx >> 6, l = idx & 63;
        x0[((size_t)b * 64 + c) * TL + l0 + l] = ot[c * 65 + l];
    }
}

// ---------------- weight prep: [u][o][i][k] f32 -> [u][k][o][i] bf16 hi/lo ----------------
__global__ __launch_bounds__(256) void k_prepw_mfma(
    const float* __restrict__ w, unsigned short* __restrict__ wbh, unsigned short* __restrict__ wbl)
{
    int idx = blockIdx.x * 256 + threadIdx.x;
    if (idx >= NRESU * 11 * 64 * 64) return;
    int i = idx & 63;
    int rest = idx >> 6;
    int o = rest & 63;
    rest >>= 6;
    int k = rest % 11;
    int u = rest / 11;
    float v = w[(((size_t)u * 64 + o) * 64 + i) * 11 + k];
    unsigned short hb = f2bf(v);
    float lo = v - bf2f(hb);
    wbh[idx] = hb;
    wbl[idx] = f2bf(lo);
}

// ---------------- residual conv k=11 pad=5 via MFMA (3-term split bf16) ----------------
// Block: 1 batch x 64 o x 128 l.  Y[l][o] = sum_k sum_i XT[l+k][i] * Wk[o][i].
// A-frag: lane&15 = Y-row(l), K = i (XT transposed tile in LDS, hi/lo).
// B-frag: lane&15 = Y-col(o), K = i (weights [k][o][i] bf16 from L2).
// D: col=lane&15(o), row=(lane>>4)*4+reg(l)  -- same verified mapping as k_lstm.
__global__ __launch_bounds__(256) void k_resconv_mfma(
    const float* __restrict__ in, float* __restrict__ out,
    const unsigned short* __restrict__ wbh, const unsigned short* __restrict__ wbl,
    const float* __restrict__ bias,
    const float* __restrict__ bg, const float* __restrict__ bb,
    const float* __restrict__ bm, const float* __restrict__ bv,
    int accumulate)
{
    __shared__ float sscale[64], sshift[64];
    __shared__ __align__(16) char smem[41472];
    unsigned short* XTH = (unsigned short*)smem;           // [144][72]
    unsigned short* XTL = XTH + 144 * 72;                  // [144][72]
    float* Yb = (float*)smem;                              // [128][66] overlay (post-MFMA)

    int tid = threadIdx.x;
    int b = blockIdx.x >> 4;
    int l0 = (blockIdx.x & 15) << 7;
    int lane = tid & 63;
    int wv = tid >> 6;
    int l15 = lane & 15, l4 = lane >> 4;

    if (tid < 64) {
        float sc = bg[tid] * rsqrtf(bv[tid] + 1e-5f);
        sscale[tid] = sc;
        sshift[tid] = bb[tid] - bm[tid] * sc;
    }
    __syncthreads();

    // ---- stage transposed BN+ReLU bf16 hi/lo tile: XT[ll][i], ll = l - (l0-5) ----
    {
        int i = tid >> 2, ll0 = (tid & 3) * 36;
        float sc = sscale[i], sh = sshift[i];
        const float* ip = in + ((size_t)b * 64 + i) * TL;
#pragma unroll
        for (int j = 0; j < 36; j++) {
            int ll = ll0 + j;
            int l = l0 - 5 + ll;
            float v = 0.0f;
            if (l >= 0 && l < TL) v = fmaxf(ip[l] * sc + sh, 0.0f);
            unsigned short hb = f2bf(v);
            float lo = v - bf2f(hb);
            XTH[ll * 72 + i] = hb;
            XTL[ll * 72 + i] = f2bf(lo);
        }
    }
    __syncthreads();

    // ---- MFMA main loop: wave wv owns l-tiles {2wv, 2wv+1} x all 4 o-tiles ----
    f32x4 acc[2][4];
#pragma unroll
    for (int s = 0; s < 2; s++)
#pragma unroll
        for (int ot = 0; ot < 4; ot++) acc[s][ot] = (f32x4){0, 0, 0, 0};

    for (int k = 0; k < 11; k++) {
#pragma unroll
        for (int ic = 0; ic < 2; ic++) {
            bhalf8 ah[2], al[2];
#pragma unroll
            for (int s = 0; s < 2; s++) {
                int row = (wv * 2 + s) * 16 + l15 + k;
                ah[s] = *(const bhalf8*)&XTH[row * 72 + ic * 32 + l4 * 8];
                al[s] = *(const bhalf8*)&XTL[row * 72 + ic * 32 + l4 * 8];
            }
#pragma unroll
            for (int ot = 0; ot < 4; ot++) {
                size_t woff = ((size_t)(k * 64 + ot * 16 + l15)) * 64 + ic * 32 + l4 * 8;
                bhalf8 bh = *(const bhalf8*)&wbh[woff];
                bhalf8 bl = *(const bhalf8*)&wbl[woff];
#pragma unroll
                for (int s = 0; s < 2; s++) {
                    acc[s][ot] = __builtin_amdgcn_mfma_f32_16x16x32_bf16(ah[s], bh, acc[s][ot], 0, 0, 0);
                    acc[s][ot] = __builtin_amdgcn_mfma_f32_16x16x32_bf16(al[s], bh, acc[s][ot], 0, 0, 0);
                    acc[s][ot] = __builtin_amdgcn_mfma_f32_16x16x32_bf16(ah[s], bl, acc[s][ot], 0, 0, 0);
                }
            }
        }
    }
    __syncthreads();   // all XT reads done; overlay Yb on same LDS

    // ---- bounce Y through LDS for coalesced epilogue ----
#pragma unroll
    for (int s = 0; s < 2; s++)
#pragma unroll
        for (int ot = 0; ot < 4; ot++)
#pragma unroll
            for (int r = 0; r < 4; r++)
                Yb[((wv * 2 + s) * 16 + l4 * 4 + r) * 66 + ot * 16 + l15] = acc[s][ot][r];
    __syncthreads();

    // ---- epilogue: bias + optional residual accumulate, write out ----
    {
        int o = tid >> 2, ls0 = (tid & 3) * 32;
        float bsv = bias[o];
        float* op = out + ((size_t)b * 64 + o) * TL + l0 + ls0;
        if (accumulate) {
#pragma unroll
            for (int j = 0; j < 32; j++) op[j] += Yb[(ls0 + j) * 66 + o] + bsv;
        } else {
#pragma unroll
            for (int j = 0; j < 32; j++) op[j] = Yb[(ls0 + j) * 66 + o] + bsv;
        }
    }
}

// ---------------- transpose+cast: [NB][64][TL] f32 -> [TL][NB*64] bf16 ----------------
__global__ __launch_bounds__(256) void k_transpose(
    const float* __restrict__ x0, unsigned short* __restrict__ Xbf)
{
    __shared__ float t[64 * 65];
    int tid = threadIdx.x;
    int b = blockIdx.x >> 5;
    int t0 = (blockIdx.x & 31) << 6;
    for (int r = 0; r < 16; r++) {
        int idx = tid + 256 * r;
        int c = idx >> 6, tt = idx & 63;
        t[c * 65 + tt] = x0[((size_t)b * 64 + c) * TL + t0 + tt];
    }
    __syncthreads();
    for (int r = 0; r < 16; r++) {
        int idx = tid + 256 * r;
        int tt = idx >> 6, c = idx & 63;
        Xbf[((size_t)(t0 + tt)) * (NB * NH) + b * 64 + c] = f2bf(t[c * 65 + tt]);
    }
}

// ---------------- pipelined 10-layer LSTM (round-12, passing, unchanged) ----------------
__global__ __launch_bounds__(512) void k_lstm(
    const unsigned short* __restrict__ Xbf,
    const float* __restrict__ w_ih, const float* __restrict__ w_hh,
    const float* __restrict__ b_ih, const float* __restrict__ b_hh,
    unsigned short* __restrict__ ring, float* __restrict__ final_h, int* prog)
{
    int bid = blockIdx.x;             // 0..79; active: bid&7 < 4
    int grp = bid & 7;
    int layer = bid >> 3;
    if (grp >= 4 || layer >= NLAY) return;
    int b0 = grp * 16;
    int tid = threadIdx.x;
    int w = tid >> 6;                 // wave 0..7
    int lane = tid & 63;
    int l15 = lane & 15, l4 = lane >> 4;
    int self = layer * 4 + grp;
    const bool has_store = (layer < NLAY - 1);
    const bool use_ring = (layer > 0);
    int brow = tid >> 5;              // batch row 0..15
    int cc0 = (tid & 31) * 2;         // u pair base (even)
    int T0 = w * 2, T1 = w * 2 + 1;   // this wave's two n-tiles (of 16)

    __shared__ __align__(16) unsigned short XH[2][16][136];   // [buf][b][x(0..63)|h(64..127)]
    __shared__ float gbuf[16][16][17];                        // [tile][b][col] padded

    bhalf8 Bh[2][4];
#pragma unroll
    for (int s = 0; s < 2; s++) {
        int n = (w * 2 + s) * 16 + l15;
        const float* rih = w_ih + ((size_t)layer * 256 + n) * 64;
        const float* rhh = w_hh + ((size_t)layer * 256 + n) * 64;
#pragma unroll
        for (int kt = 0; kt < 4; kt++) {
#pragma unroll
            for (int j = 0; j < 8; j++) {
                int k = kt * 32 + l4 * 8 + j;
                float v = (k < 64) ? rih[k] : rhh[k - 64];
                Bh[s][kt][j] = (short)f2bf(v);
            }
        }
    }
    float bv[8];
#pragma unroll
    for (int g = 0; g < 4; g++) {
#pragma unroll
        for (int s = 0; s < 2; s++) {
            int n = g * 64 + cc0 + s;
            bv[g * 2 + s] = b_ih[layer * 256 + n] + b_hh[layer * 256 + n];
        }
    }
    for (int idx = tid; idx < 2 * 16 * 64; idx += 512) {
        XH[idx >> 10][(idx >> 6) & 15][64 + (idx & 63)] = 0;
    }
    float cst[2] = {0.f, 0.f};

    int* p_self = prog + self * 32;
    int* p_prev = prog + (self - 4) * 32;
    int* p_next = prog + (self + 4) * 32;
    int cached_prev = 0, cached_next = 0;

#define POLL_GE(ptr, tgt, cachev)                                                     \
    if (cachev < (tgt)) {                                                             \
        int v_; long g_ = 0;                                                          \
        while ((v_ = __hip_atomic_load(ptr, __ATOMIC_ACQUIRE,                         \
                        __HIP_MEMORY_SCOPE_AGENT)) < (tgt) && ++g_ < 1500000)         \
            __builtin_amdgcn_s_sleep(2);                                              \
        cachev = v_;                                                                  \
    }

    if (tid == 0 && layer > 0) { POLL_GE(p_prev, 32, cached_prev); }
    __syncthreads();
    unsigned px[4];
    {
        unsigned p0;
        if (!use_ring) {
            const unsigned short* s0 = Xbf + (size_t)(b0 + brow) * 64 + cc0;
            asm volatile("global_load_dword %0, %1, off" : "=&v"(p0) : "v"(s0) : "memory");
        } else {
            const unsigned short* s0 = ring + ((size_t)(layer - 1) * RSTEP) * 4096 + (b0 + brow) * 64 + cc0;
            asm volatile("global_load_dword %0, %1, off sc0 sc1" : "=&v"(p0) : "v"(s0) : "memory");
        }
        asm volatile("s_waitcnt vmcnt(0)" ::: "memory");
        __builtin_amdgcn_sched_barrier(0);
        *(unsigned*)&XH[0][brow][cc0] = p0;
#pragma unroll
        for (int pre = 1; pre <= 3; pre++) {
            if (!use_ring) {
                const unsigned short* sp = Xbf + ((size_t)pre * NB + b0 + brow) * 64 + cc0;
                asm volatile("global_load_dword %0, %1, off" : "=&v"(px[pre]) : "v"(sp) : "memory");
            } else {
                const unsigned short* sp = ring + ((size_t)(layer - 1) * RSTEP + pre) * 4096 + (b0 + brow) * 64 + cc0;
                asm volatile("global_load_dword %0, %1, off sc0 sc1" : "=&v"(px[pre]) : "v"(sp) : "memory");
            }
        }
    }
    asm volatile("s_waitcnt vmcnt(0)" ::: "memory");
    __builtin_amdgcn_sched_barrier(0);
    __syncthreads();

    for (int t0 = 0; t0 < TL; t0 += 8) {
#pragma unroll
        for (int ts = 0; ts < 8; ++ts) {
            const int p = ts & 1, q = p ^ 1;
            const int t = t0 + ts;
            const int cons = (ts + 1) & 3;
            const int pref = ts & 3;

            f32x4 Acc0 = {0, 0, 0, 0}, Acc1 = {0, 0, 0, 0};
#pragma unroll
            for (int kt = 0; kt < 4; kt++) {
                bhalf8 Ah = *(const bhalf8*)&XH[p][l15][kt * 32 + l4 * 8];
                Acc0 = __builtin_amdgcn_mfma_f32_16x16x32_bf16(Ah, Bh[0][kt], Acc0, 0, 0, 0);
                Acc1 = __builtin_amdgcn_mfma_f32_16x16x32_bf16(Ah, Bh[1][kt], Acc1, 0, 0, 0);
            }
#pragma unroll
            for (int r = 0; r < 4; r++) {
                gbuf[T0][l4 * 4 + r][l15] = Acc0[r];
                gbuf[T1][l4 * 4 + r][l15] = Acc1[r];
            }
            asm volatile("s_waitcnt lgkmcnt(0)" ::: "memory");
            __builtin_amdgcn_s_barrier();
            __builtin_amdgcn_sched_barrier(0);

            if (has_store) { asm volatile("s_waitcnt vmcnt(4)" ::: "memory"); }
            else           { asm volatile("s_waitcnt vmcnt(2)" ::: "memory"); }
            __builtin_amdgcn_sched_barrier(0);

            *(unsigned*)&XH[q][brow][cc0] = px[cons];

            int tb = cc0 >> 4, cb = cc0 & 15;
            float hv[2];
#pragma unroll
            for (int s = 0; s < 2; s++) {
                float gi = gbuf[0 * 4 + tb][brow][cb + s] + bv[0 + s];
                float gf = gbuf[1 * 4 + tb][brow][cb + s] + bv[2 + s];
                float gg = gbuf[2 * 4 + tb][brow][cb + s] + bv[4 + s];
                float go = gbuf[3 * 4 + tb][brow][cb + s] + bv[6 + s];
                float c = fast_sigmoid(gf) * cst[s] + fast_sigmoid(gi) * fast_tanh(gg);
                cst[s] = c;
                hv[s] = fast_sigmoid(go) * fast_tanh(c);
            }
            unsigned hw = ((unsigned)f2bf(hv[1]) << 16) | (unsigned)f2bf(hv[0]);

            *(unsigned*)&XH[q][brow][64 + cc0] = hw;
            if (has_store) {
                unsigned short* ap = ring + ((size_t)layer * RSTEP + (t & 63)) * 4096 + (b0 + brow) * 64 + cc0;
                asm volatile("global_store_dword %0, %1, off sc0 sc1" :: "v"(ap), "v"(hw) : "memory");
            } else if (t == TL - 1) {
                final_h[(b0 + brow) * NH + cc0] = hv[0];
                final_h[(b0 + brow) * NH + cc0 + 1] = hv[1];
            }

            {
                int tt = t + 4; if (tt > TL - 1) tt = TL - 1;
                if (!use_ring) {
                    const unsigned short* sp = Xbf + ((size_t)tt * NB + b0 + brow) * 64 + cc0;
                    asm volatile("global_load_dword %0, %1, off" : "=&v"(px[pref]) : "v"(sp) : "memory");
                } else {
                    const unsigned short* sp = ring + ((size_t)(layer - 1) * RSTEP + (tt & 63)) * 4096 + (b0 + brow) * 64 + cc0;
                    asm volatile("global_load_dword %0, %1, off sc0 sc1" : "=&v"(px[pref]) : "v"(sp) : "memory");
                }
            }

            asm volatile("s_waitcnt lgkmcnt(0)" ::: "memory");
            __builtin_amdgcn_s_barrier();
            __builtin_amdgcn_sched_barrier(0);
        }

        if (has_store) { asm volatile("s_waitcnt vmcnt(1)" ::: "memory"); }
        __builtin_amdgcn_s_barrier();
        __builtin_amdgcn_sched_barrier(0);
        if (tid == 0) {
            __hip_atomic_store(p_self, t0, __ATOMIC_RELEASE, __HIP_MEMORY_SCOPE_AGENT);
            int nt0 = t0 + 8;
            if (nt0 < TL) {
                if (use_ring) {
                    int tgt = nt0 + 16; if (tgt > TL) tgt = TL;
                    POLL_GE(p_prev, tgt, cached_prev);
                }
                if (has_store) {
                    int need = nt0 - 64;
                    if (need > 0) { POLL_GE(p_next, need, cached_next); }
                }
            }
        }
        __builtin_amdgcn_s_barrier();
        __builtin_amdgcn_sched_barrier(0);
    }

    asm volatile("s_waitcnt vmcnt(0)" ::: "memory");
    __builtin_amdgcn_s_barrier();
    if (tid == 0) {
        __hip_atomic_store(p_self, TL, __ATOMIC_RELEASE, __HIP_MEMORY_SCOPE_AGENT);
    }
#undef POLL_GE
}

// ---------------- head ----------------
__global__ void k_head(const float* __restrict__ fh, const float* __restrict__ ow,
                       const float* __restrict__ ob, float* __restrict__ out)
{
    int b = threadIdx.x;
    if (b >= NB) return;
    const float* h = fh + b * NH;
    float l0 = ob[0], l1 = ob[1];
    for (int uu = 0; uu < 64; uu++) { l0 += h[uu] * ow[uu * 2]; l1 += h[uu] * ow[uu * 2 + 1]; }
    float m = fmaxf(l0, l1);
    float s = expf(l0 - m) + expf(l1 - m);
    float ls = m + logf(s);
    out[b * 2] = l0 - ls;
    out[b * 2 + 1] = l1 - ls;
}

extern "C" void kernel_launch(void* const* d_in, const int* in_sizes, int n_in,
                              void* d_out, int out_size, void* d_ws, size_t ws_size,
                              hipStream_t stream) {
    const float* input = (const float*)d_in[0];
    const float* c1w = (const float*)d_in[2];
    const float* c1b = (const float*)d_in[3];
    const float* c2w = (const float*)d_in[4];
    const float* c2b = (const float*)d_in[5];
    const float* bn1g = (const float*)d_in[6];
    const float* bn1b = (const float*)d_in[7];
    const float* bn1m = (const float*)d_in[8];
    const float* bn1v = (const float*)d_in[9];
    const float* rw1 = (const float*)d_in[10];
    const float* rb1 = (const float*)d_in[11];
    const float* bn2g = (const float*)d_in[12];
    const float* bn2b = (const float*)d_in[13];
    const float* bn2m = (const float*)d_in[14];
    const float* bn2v = (const float*)d_in[15];
    const float* rw2 = (const float*)d_in[16];
    const float* rb2 = (const float*)d_in[17];
    const float* wih = (const float*)d_in[18];
    const float* whh = (const float*)d_in[19];
    const float* bih = (const float*)d_in[20];
    const float* bhh = (const float*)d_in[21];
    const float* outw = (const float*)d_in[22];
    const float* outb = (const float*)d_in[23];

    float* ws = (float*)d_ws;
    float*          x0buf = ws;                              // [NB][64][TL] f32
    float*          t1buf = x0buf + 8388608;                 // [NB][64][TL] f32
    unsigned short* Xbf   = (unsigned short*)(t1buf + 8388608);  // [TL][NB*64] bf16
    unsigned short* ringb = Xbf + 8388608;                   // [9][64][64b][64u] bf16
    float*          fhbuf = (float*)(ringb + 2359296);       // [NB][NH]
    int*            progb = (int*)(fhbuf + 4096);            // 40 flags x 32
    unsigned short* wbh1  = (unsigned short*)(progb + 40 * 32);   // [3][11][64][64]
    unsigned short* wbl1  = wbh1 + NRESU * 11 * 64 * 64;
    unsigned short* wbh2  = wbl1 + NRESU * 11 * 64 * 64;
    unsigned short* wbl2  = wbh2 + NRESU * 11 * 64 * 64;

    hipMemsetAsync(progb, 0, 40 * 32 * sizeof(int), stream);

    k_prepw_mfma<<<528, 256, 0, stream>>>(rw1, wbh1, wbl1);
    k_prepw_mfma<<<528, 256, 0, stream>>>(rw2, wbh2, wbl2);
    k_frontend<<<2048, 256, 0, stream>>>(input, c1w, c1b, c2w, c2b, x0buf);
    for (int uu = 0; uu < NRESU; uu++) {
        k_resconv_mfma<<<1024, 256, 0, stream>>>(x0buf, t1buf, wbh1 + uu * 45056, wbl1 + uu * 45056,
                                                 rb1 + uu * 64, bn1g + uu * 64, bn1b + uu * 64,
                                                 bn1m + uu * 64, bn1v + uu * 64, 0);
        k_resconv_mfma<<<1024, 256, 0, stream>>>(t1buf, x0buf, wbh2 + uu * 45056, wbl2 + uu * 45056,
                                                 rb2 + uu * 64, bn2g + uu * 64, bn2b + uu * 64,
                                                 bn2m + uu * 64, bn2v + uu * 64, 1);
    }
    k_transpose<<<2048, 256, 0, stream>>>(x0buf, Xbf);
    k_lstm<<<80, 512, 0, stream>>>(Xbf, wih, whh, bih, bhh, ringb, fhbuf, progb);
    k_head<<<1, 64, 0, stream>>>(fhbuf, outw, outb, (float*)d_out);
}

// Round 14
// 2805.065 us; speedup vs baseline: 1.2635x; 1.0096x over previous
//
#include <hip/hip_runtime.h>
#include <hip/hip_bf16.h>

#define TL 2048
#define NB 64
#define NH 64
#define NLAY 10
#define NRESU 3
#define RSTEP 64

typedef float f32x4 __attribute__((ext_vector_type(4)));
typedef unsigned u32x2 __attribute__((ext_vector_type(2)));
typedef short bhalf8 __attribute__((ext_vector_type(8)));

__device__ __forceinline__ unsigned short f2bf(float f) {
    unsigned u = __float_as_uint(f);
    unsigned r = u + 0x7fffu + ((u >> 16) & 1u);
    return (unsigned short)(r >> 16);
}
__device__ __forceinline__ float bf2f(unsigned short h) {
    return __uint_as_float(((unsigned)h) << 16);
}
__device__ __forceinline__ float fast_sigmoid(float x) {
    return __builtin_amdgcn_rcpf(1.0f + __expf(-x));
}
__device__ __forceinline__ float fast_tanh(float x) {
    float e = __expf(2.0f * x);
    return 1.0f - 2.0f * __builtin_amdgcn_rcpf(e + 1.0f);
}

// ---------------- frontend ----------------
__global__ __launch_bounds__(256) void k_frontend(
    const float* __restrict__ in,
    const float* __restrict__ c1w, const float* __restrict__ c1b,
    const float* __restrict__ c2w, const float* __restrict__ c2b,
    float* __restrict__ x0)
{
    __shared__ float s_c1w[128];
    __shared__ float s_c1b[32];
    __shared__ float s_c2w[64 * 33];
    __shared__ float s_c2b[64];
    __shared__ float h1[64 * 33];
    __shared__ float ot[64 * 65];
    int tid = threadIdx.x;
    int b = blockIdx.x >> 5;
    int l0 = (blockIdx.x & 31) << 6;
    if (tid < 128) s_c1w[tid] = c1w[tid];
    if (tid < 32) s_c1b[tid] = c1b[tid];
    if (tid < 64) s_c2b[tid] = c2b[tid];
    for (int r = tid; r < 2048; r += 256) s_c2w[(r >> 5) * 33 + (r & 31)] = c2w[r];
    __syncthreads();
    if (tid < 64) {
        const float* ip = in + ((size_t)b * TL + l0 + tid) * 4;
        float x0v = ip[0], x1 = ip[1], x2 = ip[2], x3 = ip[3];
#pragma unroll
        for (int o = 0; o < 32; o++) {
            float a = s_c1w[o * 4 + 0] * x0v + s_c1w[o * 4 + 1] * x1 +
                      s_c1w[o * 4 + 2] * x2 + s_c1w[o * 4 + 3] * x3 + s_c1b[o];
            h1[tid * 33 + o] = fmaxf(a, 0.0f);
        }
    }
    __syncthreads();
    {
        int o = tid & 63, lg = tid >> 6;
#pragma unroll
        for (int j = 0; j < 16; j++) {
            int l = lg * 16 + j;
            float a = s_c2b[o];
#pragma unroll
            for (int i = 0; i < 32; i++) a += h1[l * 33 + i] * s_c2w[o * 33 + i];
            ot[o * 65 + l] = fmaxf(a, 0.0f);
        }
    }
    __syncthreads();
    for (int r = 0; r < 16; r++) {
        int idx = tid + 256 * r;
        int c = idx >> 6, l = idx & 63;
        x0[((size_t)b * 64 + c) * TL + l0 + l] = ot[c * 65 + l];
    }
}

// ---------------- weight prep: [u][o][i][k] f32 -> [u][k][o][i] bf16 hi/lo ----------------
__global__ __launch_bounds__(256) void k_prepw_mfma(
    const float* __restrict__ w, unsigned short* __restrict__ wbh, unsigned short* __restrict__ wbl)
{
    int idx = blockIdx.x * 256 + threadIdx.x;
    if (idx >= NRESU * 11 * 64 * 64) return;
    int i = idx & 63;
    int rest = idx >> 6;
    int o = rest & 63;
    rest >>= 6;
    int k = rest % 11;
    int u = rest / 11;
    float v = w[(((size_t)u * 64 + o) * 64 + i) * 11 + k];
    unsigned short hb = f2bf(v);
    float lo = v - bf2f(hb);
    wbh[idx] = hb;
    wbl[idx] = f2bf(lo);
}

// ---------------- residual conv k=11 pad=5 via MFMA (3-term split bf16) ----------------
__global__ __launch_bounds__(256) void k_resconv_mfma(
    const float* __restrict__ in, float* __restrict__ out,
    const unsigned short* __restrict__ wbh, const unsigned short* __restrict__ wbl,
    const float* __restrict__ bias,
    const float* __restrict__ bg, const float* __restrict__ bb,
    const float* __restrict__ bm, const float* __restrict__ bv,
    int accumulate)
{
    __shared__ float sscale[64], sshift[64];
    __shared__ __align__(16) char smem[41472];
    unsigned short* XTH = (unsigned short*)smem;           // [144][72]
    unsigned short* XTL = XTH + 144 * 72;                  // [144][72]
    float* Yb = (float*)smem;                              // [128][66] overlay (post-MFMA)

    int tid = threadIdx.x;
    int b = blockIdx.x >> 4;
    int l0 = (blockIdx.x & 15) << 7;
    int lane = tid & 63;
    int wv = tid >> 6;
    int l15 = lane & 15, l4 = lane >> 4;

    if (tid < 64) {
        float sc = bg[tid] * rsqrtf(bv[tid] + 1e-5f);
        sscale[tid] = sc;
        sshift[tid] = bb[tid] - bm[tid] * sc;
    }
    __syncthreads();

    {
        int i = tid >> 2, ll0 = (tid & 3) * 36;
        float sc = sscale[i], sh = sshift[i];
        const float* ip = in + ((size_t)b * 64 + i) * TL;
#pragma unroll
        for (int j = 0; j < 36; j++) {
            int ll = ll0 + j;
            int l = l0 - 5 + ll;
            float v = 0.0f;
            if (l >= 0 && l < TL) v = fmaxf(ip[l] * sc + sh, 0.0f);
            unsigned short hb = f2bf(v);
            float lo = v - bf2f(hb);
            XTH[ll * 72 + i] = hb;
            XTL[ll * 72 + i] = f2bf(lo);
        }
    }
    __syncthreads();

    f32x4 acc[2][4];
#pragma unroll
    for (int s = 0; s < 2; s++)
#pragma unroll
        for (int ot = 0; ot < 4; ot++) acc[s][ot] = (f32x4){0, 0, 0, 0};

    for (int k = 0; k < 11; k++) {
#pragma unroll
        for (int ic = 0; ic < 2; ic++) {
            bhalf8 ah[2], al[2];
#pragma unroll
            for (int s = 0; s < 2; s++) {
                int row = (wv * 2 + s) * 16 + l15 + k;
                ah[s] = *(const bhalf8*)&XTH[row * 72 + ic * 32 + l4 * 8];
                al[s] = *(const bhalf8*)&XTL[row * 72 + ic * 32 + l4 * 8];
            }
#pragma unroll
            for (int ot = 0; ot < 4; ot++) {
                size_t woff = ((size_t)(k * 64 + ot * 16 + l15)) * 64 + ic * 32 + l4 * 8;
                bhalf8 bh = *(const bhalf8*)&wbh[woff];
                bhalf8 bl = *(const bhalf8*)&wbl[woff];
#pragma unroll
                for (int s = 0; s < 2; s++) {
                    acc[s][ot] = __builtin_amdgcn_mfma_f32_16x16x32_bf16(ah[s], bh, acc[s][ot], 0, 0, 0);
                    acc[s][ot] = __builtin_amdgcn_mfma_f32_16x16x32_bf16(al[s], bh, acc[s][ot], 0, 0, 0);
                    acc[s][ot] = __builtin_amdgcn_mfma_f32_16x16x32_bf16(ah[s], bl, acc[s][ot], 0, 0, 0);
                }
            }
        }
    }
    __syncthreads();

#pragma unroll
    for (int s = 0; s < 2; s++)
#pragma unroll
        for (int ot = 0; ot < 4; ot++)
#pragma unroll
            for (int r = 0; r < 4; r++)
                Yb[((wv * 2 + s) * 16 + l4 * 4 + r) * 66 + ot * 16 + l15] = acc[s][ot][r];
    __syncthreads();

    {
        int o = tid >> 2, ls0 = (tid & 3) * 32;
        float bsv = bias[o];
        float* op = out + ((size_t)b * 64 + o) * TL + l0 + ls0;
        if (accumulate) {
#pragma unroll
            for (int j = 0; j < 32; j++) op[j] += Yb[(ls0 + j) * 66 + o] + bsv;
        } else {
#pragma unroll
            for (int j = 0; j < 32; j++) op[j] = Yb[(ls0 + j) * 66 + o] + bsv;
        }
    }
}

// ---------------- transpose+cast: [NB][64][TL] f32 -> [TL][NB*64] bf16 ----------------
__global__ __launch_bounds__(256) void k_transpose(
    const float* __restrict__ x0, unsigned short* __restrict__ Xbf)
{
    __shared__ float t[64 * 65];
    int tid = threadIdx.x;
    int b = blockIdx.x >> 5;
    int t0 = (blockIdx.x & 31) << 6;
    for (int r = 0; r < 16; r++) {
        int idx = tid + 256 * r;
        int c = idx >> 6, tt = idx & 63;
        t[c * 65 + tt] = x0[((size_t)b * 64 + c) * TL + t0 + tt];
    }
    __syncthreads();
    for (int r = 0; r < 16; r++) {
        int idx = tid + 256 * r;
        int tt = idx >> 6, c = idx & 63;
        Xbf[((size_t)(t0 + tt)) * (NB * NH) + b * 64 + c] = f2bf(t[c * 65 + tt]);
    }
}

// ---------------- pipelined 10-layer LSTM: gate-aligned tiles, NO exchange, 1 barrier/step ----------------
// 40 active WGs (layer x group of 16 batches), 512 thr = 8 waves.
// Wave w owns u-range (w&3)*16+l15 for ALL 4 gates (tiles {w&3,4+,8+,12+}); waves w and
// w+4 duplicate the 16 MFMAs (redundancy is free at 11% MfmaUtil) and split nonlinearity
// by batch-half (rhalf = w>>2): each lane does 2 h-values = 10 trans ops.
// Gate exchange + barrier1 GONE. Protocol = round-12 proven (slacked polls, counted vmcnt).
__global__ __launch_bounds__(512) void k_lstm(
    const unsigned short* __restrict__ Xbf,
    const float* __restrict__ w_ih, const float* __restrict__ w_hh,
    const float* __restrict__ b_ih, const float* __restrict__ b_hh,
    unsigned short* __restrict__ ring, float* __restrict__ final_h, int* prog)
{
    int bid = blockIdx.x;             // 0..79; active: bid&7 < 4
    int grp = bid & 7;
    int layer = bid >> 3;
    if (grp >= 4 || layer >= NLAY) return;
    int b0 = grp * 16;
    int tid = threadIdx.x;
    int w = tid >> 6;                 // wave 0..7
    int lane = tid & 63;
    int l15 = lane & 15, l4 = lane >> 4;
    int w4 = w & 3;                   // tile set / u-range
    int rhalf = w >> 2;               // batch half within l4-quad
    int u = w4 * 16 + l15;            // this lane's u
    int self = layer * 4 + grp;
    const bool has_store = (layer < NLAY - 1);
    const bool use_ring = (layer > 0);
    int brow = tid >> 5;              // staging batch row 0..15
    int cc0 = (tid & 31) * 2;         // staging u pair base

    __shared__ __align__(16) unsigned short XH[2][16][136];   // [buf][b][x(0..63)|h(64..127)]

    // ---- weights: 4 gates x 4 kt for u = w4*16+l15 (64 VGPRs) ----
    bhalf8 Bh[4][4];
    float bv[4];
#pragma unroll
    for (int g = 0; g < 4; g++) {
        int n = g * 64 + u;
        const float* rih = w_ih + ((size_t)layer * 256 + n) * 64;
        const float* rhh = w_hh + ((size_t)layer * 256 + n) * 64;
        bv[g] = b_ih[layer * 256 + n] + b_hh[layer * 256 + n];
#pragma unroll
        for (int kt = 0; kt < 4; kt++) {
#pragma unroll
            for (int j = 0; j < 8; j++) {
                int k = kt * 32 + l4 * 8 + j;
                float v = (k < 64) ? rih[k] : rhh[k - 64];
                Bh[g][kt][j] = (short)f2bf(v);
            }
        }
    }
    for (int idx = tid; idx < 2 * 16 * 64; idx += 512) {
        XH[idx >> 10][(idx >> 6) & 15][64 + (idx & 63)] = 0;
    }
    float cst[2] = {0.f, 0.f};

    int* p_self = prog + self * 32;
    int* p_prev = prog + (self - 4) * 32;
    int* p_next = prog + (self + 4) * 32;
    int cached_prev = 0, cached_next = 0;

#define POLL_GE(ptr, tgt, cachev)                                                     \
    if (cachev < (tgt)) {                                                             \
        int v_; long g_ = 0;                                                          \
        while ((v_ = __hip_atomic_load(ptr, __ATOMIC_ACQUIRE,                         \
                        __HIP_MEMORY_SCOPE_AGENT)) < (tgt) && ++g_ < 1500000)         \
            __builtin_amdgcn_s_sleep(2);                                              \
        cachev = v_;                                                                  \
    }

    // ---- prologue: wait prev published>=32, stage x(0), preload x(1..3), drain ----
    if (tid == 0 && layer > 0) { POLL_GE(p_prev, 32, cached_prev); }
    __syncthreads();
    unsigned px[4];
    {
        unsigned p0;
        if (!use_ring) {
            const unsigned short* s0 = Xbf + (size_t)(b0 + brow) * 64 + cc0;
            asm volatile("global_load_dword %0, %1, off" : "=&v"(p0) : "v"(s0) : "memory");
        } else {
            const unsigned short* s0 = ring + ((size_t)(layer - 1) * RSTEP) * 4096 + (b0 + brow) * 64 + cc0;
            asm volatile("global_load_dword %0, %1, off sc0 sc1" : "=&v"(p0) : "v"(s0) : "memory");
        }
        asm volatile("s_waitcnt vmcnt(0)" ::: "memory");
        __builtin_amdgcn_sched_barrier(0);
        *(unsigned*)&XH[0][brow][cc0] = p0;
#pragma unroll
        for (int pre = 1; pre <= 3; pre++) {
            if (!use_ring) {
                const unsigned short* sp = Xbf + ((size_t)pre * NB + b0 + brow) * 64 + cc0;
                asm volatile("global_load_dword %0, %1, off" : "=&v"(px[pre]) : "v"(sp) : "memory");
            } else {
                const unsigned short* sp = ring + ((size_t)(layer - 1) * RSTEP + pre) * 4096 + (b0 + brow) * 64 + cc0;
                asm volatile("global_load_dword %0, %1, off sc0 sc1" : "=&v"(px[pre]) : "v"(sp) : "memory");
            }
        }
    }
    asm volatile("s_waitcnt vmcnt(0)" ::: "memory");
    __builtin_amdgcn_sched_barrier(0);
    __syncthreads();

    for (int t0 = 0; t0 < TL; t0 += 8) {
#pragma unroll
        for (int ts = 0; ts < 8; ++ts) {
            const int p = ts & 1, q = p ^ 1;
            const int t = t0 + ts;
            const int cons = (ts + 1) & 3;   // px slot holding x(t+1)
            const int pref = ts & 3;         // slot to refill with x(t+4)

            // ---- gates for u (all 4), batches = D-rows (bias in init) ----
            f32x4 acc[4];
#pragma unroll
            for (int g = 0; g < 4; g++) acc[g] = (f32x4){bv[g], bv[g], bv[g], bv[g]};
#pragma unroll
            for (int kt = 0; kt < 4; kt++) {
                bhalf8 Ah = *(const bhalf8*)&XH[p][l15][kt * 32 + l4 * 8];
                acc[0] = __builtin_amdgcn_mfma_f32_16x16x32_bf16(Ah, Bh[0][kt], acc[0], 0, 0, 0);
                acc[1] = __builtin_amdgcn_mfma_f32_16x16x32_bf16(Ah, Bh[1][kt], acc[1], 0, 0, 0);
                acc[2] = __builtin_amdgcn_mfma_f32_16x16x32_bf16(Ah, Bh[2][kt], acc[2], 0, 0, 0);
                acc[3] = __builtin_amdgcn_mfma_f32_16x16x32_bf16(Ah, Bh[3][kt], acc[3], 0, 0, 0);
            }

            // ---- nonlinearity: this wave's batch half (2 h-values/lane) ----
            float hv[2];
            unsigned short hb[2];
#pragma unroll
            for (int rr = 0; rr < 2; rr++) {
                int r = rhalf * 2 + rr;
                float c = fast_sigmoid(acc[1][r]) * cst[rr] +
                          fast_sigmoid(acc[0][r]) * fast_tanh(acc[2][r]);
                cst[rr] = c;
                float h = fast_sigmoid(acc[3][r]) * fast_tanh(c);
                hv[rr] = h;
                hb[rr] = f2bf(h);
            }

            // ---- counted wait for x(t+1) (loaded 3 steps ago) ----
            if (has_store) { asm volatile("s_waitcnt vmcnt(6)" ::: "memory"); }
            else           { asm volatile("s_waitcnt vmcnt(2)" ::: "memory"); }
            __builtin_amdgcn_sched_barrier(0);

            // ---- stage x(t+1) into buf q (1 dword, no VALU) ----
            *(unsigned*)&XH[q][brow][cc0] = px[cons];

            // ---- own h into buf q + ring ----
#pragma unroll
            for (int rr = 0; rr < 2; rr++) {
                int b = l4 * 4 + rhalf * 2 + rr;
                XH[q][b][64 + u] = hb[rr];
                if (has_store) {
                    unsigned short* ap = ring + ((size_t)layer * RSTEP + (t & 63)) * 4096 + (b0 + b) * 64 + u;
                    unsigned val = hb[rr];
                    asm volatile("global_store_short %0, %1, off sc0 sc1" :: "v"(ap), "v"(val) : "memory");
                } else if (t == TL - 1) {
                    final_h[(b0 + b) * NH + u] = hv[rr];
                }
            }

            // ---- prefetch x(t+4) ----
            {
                int tt = t + 4; if (tt > TL - 1) tt = TL - 1;
                if (!use_ring) {
                    const unsigned short* sp = Xbf + ((size_t)tt * NB + b0 + brow) * 64 + cc0;
                    asm volatile("global_load_dword %0, %1, off" : "=&v"(px[pref]) : "v"(sp) : "memory");
                } else {
                    const unsigned short* sp = ring + ((size_t)(layer - 1) * RSTEP + (tt & 63)) * 4096 + (b0 + brow) * 64 + cc0;
                    asm volatile("global_load_dword %0, %1, off sc0 sc1" : "=&v"(px[pref]) : "v"(sp) : "memory");
                }
            }

            asm volatile("s_waitcnt lgkmcnt(0)" ::: "memory");
            __builtin_amdgcn_s_barrier();
            __builtin_amdgcn_sched_barrier(0);
        }

        // ---- superstep end: drain stores (vmcnt(1)), publish, slacked polls ----
        if (has_store) { asm volatile("s_waitcnt vmcnt(1)" ::: "memory"); }
        __builtin_amdgcn_s_barrier();
        __builtin_amdgcn_sched_barrier(0);
        if (tid == 0) {
            __hip_atomic_store(p_self, t0, __ATOMIC_RELEASE, __HIP_MEMORY_SCOPE_AGENT);
            int nt0 = t0 + 8;
            if (nt0 < TL) {
                if (use_ring) {
                    int tgt = nt0 + 16; if (tgt > TL) tgt = TL;
                    POLL_GE(p_prev, tgt, cached_prev);
                }
                if (has_store) {
                    int need = nt0 - 64;
                    if (need > 0) { POLL_GE(p_next, need, cached_next); }
                }
            }
        }
        __builtin_amdgcn_s_barrier();
        __builtin_amdgcn_sched_barrier(0);
    }

    // ---- epilogue: full drain, final publish ----
    asm volatile("s_waitcnt vmcnt(0)" ::: "memory");
    __builtin_amdgcn_s_barrier();
    if (tid == 0) {
        __hip_atomic_store(p_self, TL, __ATOMIC_RELEASE, __HIP_MEMORY_SCOPE_AGENT);
    }
#undef POLL_GE
}

// ---------------- head ----------------
__global__ void k_head(const float* __restrict__ fh, const float* __restrict__ ow,
                       const float* __restrict__ ob, float* __restrict__ out)
{
    int b = threadIdx.x;
    if (b >= NB) return;
    const float* h = fh + b * NH;
    float l0 = ob[0], l1 = ob[1];
    for (int uu = 0; uu < 64; uu++) { l0 += h[uu] * ow[uu * 2]; l1 += h[uu] * ow[uu * 2 + 1]; }
    float m = fmaxf(l0, l1);
    float s = expf(l0 - m) + expf(l1 - m);
    float ls = m + logf(s);
    out[b * 2] = l0 - ls;
    out[b * 2 + 1] = l1 - ls;
}

extern "C" void kernel_launch(void* const* d_in, const int* in_sizes, int n_in,
                              void* d_out, int out_size, void* d_ws, size_t ws_size,
                              hipStream_t stream) {
    const float* input = (const float*)d_in[0];
    const float* c1w = (const float*)d_in[2];
    const float* c1b = (const float*)d_in[3];
    const float* c2w = (const float*)d_in[4];
    const float* c2b = (const float*)d_in[5];
    const float* bn1g = (const float*)d_in[6];
    const float* bn1b = (const float*)d_in[7];
    const float* bn1m = (const float*)d_in[8];
    const float* bn1v = (const float*)d_in[9];
    const float* rw1 = (const float*)d_in[10];
    const float* rb1 = (const float*)d_in[11];
    const float* bn2g = (const float*)d_in[12];
    const float* bn2b = (const float*)d_in[13];
    const float* bn2m = (const float*)d_in[14];
    const float* bn2v = (const float*)d_in[15];
    const float* rw2 = (const float*)d_in[16];
    const float* rb2 = (const float*)d_in[17];
    const float* wih = (const float*)d_in[18];
    const float* whh = (const float*)d_in[19];
    const float* bih = (const float*)d_in[20];
    const float* bhh = (const float*)d_in[21];
    const float* outw = (const float*)d_in[22];
    const float* outb = (const float*)d_in[23];

    float* ws = (float*)d_ws;
    float*          x0buf = ws;                              // [NB][64][TL] f32
    float*          t1buf = x0buf + 8388608;                 // [NB][64][TL] f32
    unsigned short* Xbf   = (unsigned short*)(t1buf + 8388608);  // [TL][NB*64] bf16
    unsigned short* ringb = Xbf + 8388608;                   // [9][64][64b][64u] bf16
    float*          fhbuf = (float*)(ringb + 2359296);       // [NB][NH]
    int*            progb = (int*)(fhbuf + 4096);            // 40 flags x 32
    unsigned short* wbh1  = (unsigned short*)(progb + 40 * 32);   // [3][11][64][64]
    unsigned short* wbl1  = wbh1 + NRESU * 11 * 64 * 64;
    unsigned short* wbh2  = wbl1 + NRESU * 11 * 64 * 64;
    unsigned short* wbl2  = wbh2 + NRESU * 11 * 64 * 64;

    hipMemsetAsync(progb, 0, 40 * 32 * sizeof(int), stream);

    k_prepw_mfma<<<528, 256, 0, stream>>>(rw1, wbh1, wbl1);
    k_prepw_mfma<<<528, 256, 0, stream>>>(rw2, wbh2, wbl2);
    k_frontend<<<2048, 256, 0, stream>>>(input, c1w, c1b, c2w, c2b, x0buf);
    for (int uu = 0; uu < NRESU; uu++) {
        k_resconv_mfma<<<1024, 256, 0, stream>>>(x0buf, t1buf, wbh1 + uu * 45056, wbl1 + uu * 45056,
                                                 rb1 + uu * 64, bn1g + uu * 64, bn1b + uu * 64,
                                                 bn1m + uu * 64, bn1v + uu * 64, 0);
        k_resconv_mfma<<<1024, 256, 0, stream>>>(t1buf, x0buf, wbh2 + uu * 45056, wbl2 + uu * 45056,
                                                 rb2 + uu * 64, bn2g + uu * 64, bn2b + uu * 64,
                                                 bn2m + uu * 64, bn2v + uu * 64, 1);
    }
    k_transpose<<<2048, 256, 0, stream>>>(x0buf, Xbf);
    k_lstm<<<80, 512, 0, stream>>>(Xbf, wih, whh, bih, bhh, ringb, fhbuf, progb);
    k_head<<<1, 64, 0, stream>>>(fhbuf, outw, outb, (float*)d_out);
}

// Round 15
// 2681.492 us; speedup vs baseline: 1.3218x; 1.0461x over previous
//
#include <hip/hip_runtime.h>
#include <hip/hip_bf16.h>

#define TL 2048
#define NB 64
#define NH 64
#define NLAY 10
#define NRESU 3
#define RSTEP 64

typedef float f32x4 __attribute__((ext_vector_type(4)));
typedef short bhalf8 __attribute__((ext_vector_type(8)));

__device__ __forceinline__ unsigned short f2bf(float f) {
    unsigned u = __float_as_uint(f);
    unsigned r = u + 0x7fffu + ((u >> 16) & 1u);
    return (unsigned short)(r >> 16);
}
__device__ __forceinline__ float bf2f(unsigned short h) {
    return __uint_as_float(((unsigned)h) << 16);
}
__device__ __forceinline__ float fast_sigmoid(float x) {
    return __builtin_amdgcn_rcpf(1.0f + __expf(-x));
}
// raw 2^x / 2^-x (v_exp_f32; neg is a free input modifier)
__device__ __forceinline__ float exp2_pos(float x) {
    float r; asm("v_exp_f32 %0, %1" : "=v"(r) : "v"(x)); return r;
}
__device__ __forceinline__ float exp2_neg(float x) {
    float r; asm("v_exp_f32 %0, -%1" : "=v"(r) : "v"(x)); return r;
}

// ---------------- frontend ----------------
__global__ __launch_bounds__(256) void k_frontend(
    const float* __restrict__ in,
    const float* __restrict__ c1w, const float* __restrict__ c1b,
    const float* __restrict__ c2w, const float* __restrict__ c2b,
    float* __restrict__ x0)
{
    __shared__ float s_c1w[128];
    __shared__ float s_c1b[32];
    __shared__ float s_c2w[64 * 33];
    __shared__ float s_c2b[64];
    __shared__ float h1[64 * 33];
    __shared__ float ot[64 * 65];
    int tid = threadIdx.x;
    int b = blockIdx.x >> 5;
    int l0 = (blockIdx.x & 31) << 6;
    if (tid < 128) s_c1w[tid] = c1w[tid];
    if (tid < 32) s_c1b[tid] = c1b[tid];
    if (tid < 64) s_c2b[tid] = c2b[tid];
    for (int r = tid; r < 2048; r += 256) s_c2w[(r >> 5) * 33 + (r & 31)] = c2w[r];
    __syncthreads();
    if (tid < 64) {
        const float* ip = in + ((size_t)b * TL + l0 + tid) * 4;
        float x0v = ip[0], x1 = ip[1], x2 = ip[2], x3 = ip[3];
#pragma unroll
        for (int o = 0; o < 32; o++) {
            float a = s_c1w[o * 4 + 0] * x0v + s_c1w[o * 4 + 1] * x1 +
                      s_c1w[o * 4 + 2] * x2 + s_c1w[o * 4 + 3] * x3 + s_c1b[o];
            h1[tid * 33 + o] = fmaxf(a, 0.0f);
        }
    }
    __syncthreads();
    {
        int o = tid & 63, lg = tid >> 6;
#pragma unroll
        for (int j = 0; j < 16; j++) {
            int l = lg * 16 + j;
            float a = s_c2b[o];
#pragma unroll
            for (int i = 0; i < 32; i++) a += h1[l * 33 + i] * s_c2w[o * 33 + i];
            ot[o * 65 + l] = fmaxf(a, 0.0f);
        }
    }
    __syncthreads();
    for (int r = 0; r < 16; r++) {
        int idx = tid + 256 * r;
        int c = idx >> 6, l = idx & 63;
        x0[((size_t)b * 64 + c) * TL + l0 + l] = ot[c * 65 + l];
    }
}

// ---------------- weight prep: [u][o][i][k] f32 -> [u][k][o][i] bf16 hi/lo ----------------
__global__ __launch_bounds__(256) void k_prepw_mfma(
    const float* __restrict__ w, unsigned short* __restrict__ wbh, unsigned short* __restrict__ wbl)
{
    int idx = blockIdx.x * 256 + threadIdx.x;
    if (idx >= NRESU * 11 * 64 * 64) return;
    int i = idx & 63;
    int rest = idx >> 6;
    int o = rest & 63;
    rest >>= 6;
    int k = rest % 11;
    int u = rest / 11;
    float v = w[(((size_t)u * 64 + o) * 64 + i) * 11 + k];
    unsigned short hb = f2bf(v);
    float lo = v - bf2f(hb);
    wbh[idx] = hb;
    wbl[idx] = f2bf(lo);
}

// ---------------- residual conv k=11 pad=5 via MFMA (3-term split bf16) ----------------
__global__ __launch_bounds__(256) void k_resconv_mfma(
    const float* __restrict__ in, float* __restrict__ out,
    const unsigned short* __restrict__ wbh, const unsigned short* __restrict__ wbl,
    const float* __restrict__ bias,
    const float* __restrict__ bg, const float* __restrict__ bb,
    const float* __restrict__ bm, const float* __restrict__ bv,
    int accumulate)
{
    __shared__ float sscale[64], sshift[64];
    __shared__ __align__(16) char smem[41472];
    unsigned short* XTH = (unsigned short*)smem;           // [144][72]
    unsigned short* XTL = XTH + 144 * 72;                  // [144][72]
    float* Yb = (float*)smem;                              // [128][66] overlay (post-MFMA)

    int tid = threadIdx.x;
    int b = blockIdx.x >> 4;
    int l0 = (blockIdx.x & 15) << 7;
    int lane = tid & 63;
    int wv = tid >> 6;
    int l15 = lane & 15, l4 = lane >> 4;

    if (tid < 64) {
        float sc = bg[tid] * rsqrtf(bv[tid] + 1e-5f);
        sscale[tid] = sc;
        sshift[tid] = bb[tid] - bm[tid] * sc;
    }
    __syncthreads();

    // ---- COALESCED stage: lane = column l, rows i = (tid>>6) + 4*it ----
    {
        int lcol = tid & 63;
        int ib = tid >> 6;
#pragma unroll
        for (int it = 0; it < 16; it++) {
            int i = ib + it * 4;
            float sc = sscale[i], sh = sshift[i];
            const float* ip = in + ((size_t)b * 64 + i) * TL;
#pragma unroll
            for (int jc = 0; jc < 3; jc++) {
                int ll = jc * 64 + lcol;
                if (ll < 138) {
                    int l = l0 - 5 + ll;
                    float v = 0.0f;
                    if (l >= 0 && l < TL) v = fmaxf(ip[l] * sc + sh, 0.0f);
                    unsigned short hb = f2bf(v);
                    float lo = v - bf2f(hb);
                    XTH[ll * 72 + i] = hb;
                    XTL[ll * 72 + i] = f2bf(lo);
                }
            }
        }
    }
    __syncthreads();

    f32x4 acc[2][4];
#pragma unroll
    for (int s = 0; s < 2; s++)
#pragma unroll
        for (int ot = 0; ot < 4; ot++) acc[s][ot] = (f32x4){0, 0, 0, 0};

    for (int k = 0; k < 11; k++) {
#pragma unroll
        for (int ic = 0; ic < 2; ic++) {
            bhalf8 ah[2], al[2];
#pragma unroll
            for (int s = 0; s < 2; s++) {
                int row = (wv * 2 + s) * 16 + l15 + k;
                ah[s] = *(const bhalf8*)&XTH[row * 72 + ic * 32 + l4 * 8];
                al[s] = *(const bhalf8*)&XTL[row * 72 + ic * 32 + l4 * 8];
            }
#pragma unroll
            for (int ot = 0; ot < 4; ot++) {
                size_t woff = ((size_t)(k * 64 + ot * 16 + l15)) * 64 + ic * 32 + l4 * 8;
                bhalf8 bh = *(const bhalf8*)&wbh[woff];
                bhalf8 bl = *(const bhalf8*)&wbl[woff];
#pragma unroll
                for (int s = 0; s < 2; s++) {
                    acc[s][ot] = __builtin_amdgcn_mfma_f32_16x16x32_bf16(ah[s], bh, acc[s][ot], 0, 0, 0);
                    acc[s][ot] = __builtin_amdgcn_mfma_f32_16x16x32_bf16(al[s], bh, acc[s][ot], 0, 0, 0);
                    acc[s][ot] = __builtin_amdgcn_mfma_f32_16x16x32_bf16(ah[s], bl, acc[s][ot], 0, 0, 0);
                }
            }
        }
    }
    __syncthreads();

#pragma unroll
    for (int s = 0; s < 2; s++)
#pragma unroll
        for (int ot = 0; ot < 4; ot++)
#pragma unroll
            for (int r = 0; r < 4; r++)
                Yb[((wv * 2 + s) * 16 + l4 * 4 + r) * 66 + ot * 16 + l15] = acc[s][ot][r];
    __syncthreads();

    {
        int o = tid >> 2, ls0 = (tid & 3) * 32;
        float bsv = bias[o];
        float* op = out + ((size_t)b * 64 + o) * TL + l0 + ls0;
        if (accumulate) {
#pragma unroll
            for (int j = 0; j < 32; j++) op[j] += Yb[(ls0 + j) * 66 + o] + bsv;
        } else {
#pragma unroll
            for (int j = 0; j < 32; j++) op[j] = Yb[(ls0 + j) * 66 + o] + bsv;
        }
    }
}

// ---------------- transpose+cast: [NB][64][TL] f32 -> [TL][NB*64] bf16 ----------------
__global__ __launch_bounds__(256) void k_transpose(
    const float* __restrict__ x0, unsigned short* __restrict__ Xbf)
{
    __shared__ float t[64 * 65];
    int tid = threadIdx.x;
    int b = blockIdx.x >> 5;
    int t0 = (blockIdx.x & 31) << 6;
    for (int r = 0; r < 16; r++) {
        int idx = tid + 256 * r;
        int c = idx >> 6, tt = idx & 63;
        t[c * 65 + tt] = x0[((size_t)b * 64 + c) * TL + t0 + tt];
    }
    __syncthreads();
    for (int r = 0; r < 16; r++) {
        int idx = tid + 256 * r;
        int tt = idx >> 6, c = idx & 63;
        Xbf[((size_t)(t0 + tt)) * (NB * NH) + b * 64 + c] = f2bf(t[c * 65 + tt]);
    }
}

// ---------------- pipelined 10-layer LSTM: gate-aligned + exp2-native nonlin + cvt_pk ----------------
// As round-14 (passing), with: weights/biases pre-scaled by log2e (i,f,o) / 2*log2e (g)
// -> sigmoid = rcp(1+exp2(-acc)) [neg modifier free], tanh(g) = 1-2*rcp(exp2(acc)+1);
// h-pair packed via v_cvt_pk_bf16_f32 (RNE, bit-identical to f2bf).
__global__ __launch_bounds__(512) void k_lstm(
    const unsigned short* __restrict__ Xbf,
    const float* __restrict__ w_ih, const float* __restrict__ w_hh,
    const float* __restrict__ b_ih, const float* __restrict__ b_hh,
    unsigned short* __restrict__ ring, float* __restrict__ final_h, int* prog)
{
    int bid = blockIdx.x;             // 0..79; active: bid&7 < 4
    int grp = bid & 7;
    int layer = bid >> 3;
    if (grp >= 4 || layer >= NLAY) return;
    int b0 = grp * 16;
    int tid = threadIdx.x;
    int w = tid >> 6;                 // wave 0..7
    int lane = tid & 63;
    int l15 = lane & 15, l4 = lane >> 4;
    int w4 = w & 3;                   // tile set / u-range
    int rhalf = w >> 2;               // batch half within l4-quad
    int u = w4 * 16 + l15;            // this lane's u
    int self = layer * 4 + grp;
    const bool has_store = (layer < NLAY - 1);
    const bool use_ring = (layer > 0);
    int brow = tid >> 5;              // staging batch row 0..15
    int cc0 = (tid & 31) * 2;         // staging u pair base

    __shared__ __align__(16) unsigned short XH[2][16][136];   // [buf][b][x(0..63)|h(64..127)]

    const float LOG2E = 1.44269504f;

    // ---- weights: 4 gates x 4 kt for u (pre-scaled: i,f,o x log2e ; g x 2log2e) ----
    bhalf8 Bh[4][4];
    float bv[4];
#pragma unroll
    for (int g = 0; g < 4; g++) {
        float wsc = (g == 2) ? 2.0f * LOG2E : LOG2E;
        int n = g * 64 + u;
        const float* rih = w_ih + ((size_t)layer * 256 + n) * 64;
        const float* rhh = w_hh + ((size_t)layer * 256 + n) * 64;
        bv[g] = (b_ih[layer * 256 + n] + b_hh[layer * 256 + n]) * wsc;
#pragma unroll
        for (int kt = 0; kt < 4; kt++) {
#pragma unroll
            for (int j = 0; j < 8; j++) {
                int k = kt * 32 + l4 * 8 + j;
                float v = (k < 64) ? rih[k] : rhh[k - 64];
                Bh[g][kt][j] = (short)f2bf(v * wsc);
            }
        }
    }
    for (int idx = tid; idx < 2 * 16 * 64; idx += 512) {
        XH[idx >> 10][(idx >> 6) & 15][64 + (idx & 63)] = 0;
    }
    float cst[2] = {0.f, 0.f};

    int* p_self = prog + self * 32;
    int* p_prev = prog + (self - 4) * 32;
    int* p_next = prog + (self + 4) * 32;
    int cached_prev = 0, cached_next = 0;

#define POLL_GE(ptr, tgt, cachev)                                                     \
    if (cachev < (tgt)) {                                                             \
        int v_; long g_ = 0;                                                          \
        while ((v_ = __hip_atomic_load(ptr, __ATOMIC_ACQUIRE,                         \
                        __HIP_MEMORY_SCOPE_AGENT)) < (tgt) && ++g_ < 1500000)         \
            __builtin_amdgcn_s_sleep(2);                                              \
        cachev = v_;                                                                  \
    }

    // ---- prologue ----
    if (tid == 0 && layer > 0) { POLL_GE(p_prev, 32, cached_prev); }
    __syncthreads();
    unsigned px[4];
    {
        unsigned p0;
        if (!use_ring) {
            const unsigned short* s0 = Xbf + (size_t)(b0 + brow) * 64 + cc0;
            asm volatile("global_load_dword %0, %1, off" : "=&v"(p0) : "v"(s0) : "memory");
        } else {
            const unsigned short* s0 = ring + ((size_t)(layer - 1) * RSTEP) * 4096 + (b0 + brow) * 64 + cc0;
            asm volatile("global_load_dword %0, %1, off sc0 sc1" : "=&v"(p0) : "v"(s0) : "memory");
        }
        asm volatile("s_waitcnt vmcnt(0)" ::: "memory");
        __builtin_amdgcn_sched_barrier(0);
        *(unsigned*)&XH[0][brow][cc0] = p0;
#pragma unroll
        for (int pre = 1; pre <= 3; pre++) {
            if (!use_ring) {
                const unsigned short* sp = Xbf + ((size_t)pre * NB + b0 + brow) * 64 + cc0;
                asm volatile("global_load_dword %0, %1, off" : "=&v"(px[pre]) : "v"(sp) : "memory");
            } else {
                const unsigned short* sp = ring + ((size_t)(layer - 1) * RSTEP + pre) * 4096 + (b0 + brow) * 64 + cc0;
                asm volatile("global_load_dword %0, %1, off sc0 sc1" : "=&v"(px[pre]) : "v"(sp) : "memory");
            }
        }
    }
    asm volatile("s_waitcnt vmcnt(0)" ::: "memory");
    __builtin_amdgcn_sched_barrier(0);
    __syncthreads();

    for (int t0 = 0; t0 < TL; t0 += 8) {
#pragma unroll
        for (int ts = 0; ts < 8; ++ts) {
            const int p = ts & 1, q = p ^ 1;
            const int t = t0 + ts;
            const int cons = (ts + 1) & 3;   // px slot holding x(t+1)
            const int pref = ts & 3;         // slot to refill with x(t+4)

            // ---- gates for u (all 4), bias in init ----
            f32x4 acc[4];
#pragma unroll
            for (int g = 0; g < 4; g++) acc[g] = (f32x4){bv[g], bv[g], bv[g], bv[g]};
#pragma unroll
            for (int kt = 0; kt < 4; kt++) {
                bhalf8 Ah = *(const bhalf8*)&XH[p][l15][kt * 32 + l4 * 8];
                acc[0] = __builtin_amdgcn_mfma_f32_16x16x32_bf16(Ah, Bh[0][kt], acc[0], 0, 0, 0);
                acc[1] = __builtin_amdgcn_mfma_f32_16x16x32_bf16(Ah, Bh[1][kt], acc[1], 0, 0, 0);
                acc[2] = __builtin_amdgcn_mfma_f32_16x16x32_bf16(Ah, Bh[2][kt], acc[2], 0, 0, 0);
                acc[3] = __builtin_amdgcn_mfma_f32_16x16x32_bf16(Ah, Bh[3][kt], acc[3], 0, 0, 0);
            }

            // ---- nonlinearity (exp2-native, accs pre-scaled) ----
            float hv[2];
#pragma unroll
            for (int rr = 0; rr < 2; rr++) {
                int r = rhalf * 2 + rr;
                float si = __builtin_amdgcn_rcpf(1.0f + exp2_neg(acc[0][r]));
                float sf = __builtin_amdgcn_rcpf(1.0f + exp2_neg(acc[1][r]));
                float tg = 1.0f - 2.0f * __builtin_amdgcn_rcpf(exp2_pos(acc[2][r]) + 1.0f);
                float c = sf * cst[rr] + si * tg;
                cst[rr] = c;
                float tc = 1.0f - 2.0f * __builtin_amdgcn_rcpf(exp2_pos(c * (2.0f * LOG2E)) + 1.0f);
                float so = __builtin_amdgcn_rcpf(1.0f + exp2_neg(acc[3][r]));
                hv[rr] = so * tc;
            }
            unsigned hpk;
            asm("v_cvt_pk_bf16_f32 %0, %1, %2" : "=v"(hpk) : "v"(hv[0]), "v"(hv[1]));
            unsigned hb0 = hpk & 0xffffu;
            unsigned hb1 = hpk >> 16;

            // ---- counted wait for x(t+1) (loaded 3 steps ago) ----
            if (has_store) { asm volatile("s_waitcnt vmcnt(6)" ::: "memory"); }
            else           { asm volatile("s_waitcnt vmcnt(2)" ::: "memory"); }
            __builtin_amdgcn_sched_barrier(0);

            // ---- stage x(t+1) into buf q ----
            *(unsigned*)&XH[q][brow][cc0] = px[cons];

            // ---- own h into buf q + ring ----
            {
                int bb = l4 * 4 + rhalf * 2;
                XH[q][bb][64 + u] = (unsigned short)hb0;
                XH[q][bb + 1][64 + u] = (unsigned short)hb1;
                if (has_store) {
                    unsigned short* ap0 = ring + ((size_t)layer * RSTEP + (t & 63)) * 4096 + (b0 + bb) * 64 + u;
                    asm volatile("global_store_short %0, %1, off sc0 sc1" :: "v"(ap0), "v"(hb0) : "memory");
                    asm volatile("global_store_short %0, %1, off sc0 sc1" :: "v"(ap0 + 64), "v"(hb1) : "memory");
                } else if (t == TL - 1) {
                    final_h[(b0 + bb) * NH + u] = hv[0];
                    final_h[(b0 + bb + 1) * NH + u] = hv[1];
                }
            }

            // ---- prefetch x(t+4) ----
            {
                int tt = t + 4; if (tt > TL - 1) tt = TL - 1;
                if (!use_ring) {
                    const unsigned short* sp = Xbf + ((size_t)tt * NB + b0 + brow) * 64 + cc0;
                    asm volatile("global_load_dword %0, %1, off" : "=&v"(px[pref]) : "v"(sp) : "memory");
                } else {
                    const unsigned short* sp = ring + ((size_t)(layer - 1) * RSTEP + (tt & 63)) * 4096 + (b0 + brow) * 64 + cc0;
                    asm volatile("global_load_dword %0, %1, off sc0 sc1" : "=&v"(px[pref]) : "v"(sp) : "memory");
                }
            }

            asm volatile("s_waitcnt lgkmcnt(0)" ::: "memory");
            __builtin_amdgcn_s_barrier();
            __builtin_amdgcn_sched_barrier(0);
        }

        // ---- superstep end: drain stores (vmcnt(1)), publish, slacked polls ----
        if (has_store) { asm volatile("s_waitcnt vmcnt(1)" ::: "memory"); }
        __builtin_amdgcn_s_barrier();
        __builtin_amdgcn_sched_barrier(0);
        if (tid == 0) {
            __hip_atomic_store(p_self, t0, __ATOMIC_RELEASE, __HIP_MEMORY_SCOPE_AGENT);
            int nt0 = t0 + 8;
            if (nt0 < TL) {
                if (use_ring) {
                    int tgt = nt0 + 16; if (tgt > TL) tgt = TL;
                    POLL_GE(p_prev, tgt, cached_prev);
                }
                if (has_store) {
                    int need = nt0 - 64;
                    if (need > 0) { POLL_GE(p_next, need, cached_next); }
                }
            }
        }
        __builtin_amdgcn_s_barrier();
        __builtin_amdgcn_sched_barrier(0);
    }

    // ---- epilogue ----
    asm volatile("s_waitcnt vmcnt(0)" ::: "memory");
    __builtin_amdgcn_s_barrier();
    if (tid == 0) {
        __hip_atomic_store(p_self, TL, __ATOMIC_RELEASE, __HIP_MEMORY_SCOPE_AGENT);
    }
#undef POLL_GE
}

// ---------------- head ----------------
__global__ void k_head(const float* __restrict__ fh, const float* __restrict__ ow,
                       const float* __restrict__ ob, float* __restrict__ out)
{
    int b = threadIdx.x;
    if (b >= NB) return;
    const float* h = fh + b * NH;
    float l0 = ob[0], l1 = ob[1];
    for (int uu = 0; uu < 64; uu++) { l0 += h[uu] * ow[uu * 2]; l1 += h[uu] * ow[uu * 2 + 1]; }
    float m = fmaxf(l0, l1);
    float s = expf(l0 - m) + expf(l1 - m);
    float ls = m + logf(s);
    out[b * 2] = l0 - ls;
    out[b * 2 + 1] = l1 - ls;
}

extern "C" void kernel_launch(void* const* d_in, const int* in_sizes, int n_in,
                              void* d_out, int out_size, void* d_ws, size_t ws_size,
                              hipStream_t stream) {
    const float* input = (const float*)d_in[0];
    const float* c1w = (const float*)d_in[2];
    const float* c1b = (const float*)d_in[3];
    const float* c2w = (const float*)d_in[4];
    const float* c2b = (const float*)d_in[5];
    const float* bn1g = (const float*)d_in[6];
    const float* bn1b = (const float*)d_in[7];
    const float* bn1m = (const float*)d_in[8];
    const float* bn1v = (const float*)d_in[9];
    const float* rw1 = (const float*)d_in[10];
    const float* rb1 = (const float*)d_in[11];
    const float* bn2g = (const float*)d_in[12];
    const float* bn2b = (const float*)d_in[13];
    const float* bn2m = (const float*)d_in[14];
    const float* bn2v = (const float*)d_in[15];
    const float* rw2 = (const float*)d_in[16];
    const float* rb2 = (const float*)d_in[17];
    const float* wih = (const float*)d_in[18];
    const float* whh = (const float*)d_in[19];
    const float* bih = (const float*)d_in[20];
    const float* bhh = (const float*)d_in[21];
    const float* outw = (const float*)d_in[22];
    const float* outb = (const float*)d_in[23];

    float* ws = (float*)d_ws;
    float*          x0buf = ws;                              // [NB][64][TL] f32
    float*          t1buf = x0buf + 8388608;                 // [NB][64][TL] f32
    unsigned short* Xbf   = (unsigned short*)(t1buf + 8388608);  // [TL][NB*64] bf16
    unsigned short* ringb = Xbf + 8388608;                   // [9][64][64b][64u] bf16
    float*          fhbuf = (float*)(ringb + 2359296);       // [NB][NH]
    int*            progb = (int*)(fhbuf + 4096);            // 40 flags x 32
    unsigned short* wbh1  = (unsigned short*)(progb + 40 * 32);   // [3][11][64][64]
    unsigned short* wbl1  = wbh1 + NRESU * 11 * 64 * 64;
    unsigned short* wbh2  = wbl1 + NRESU * 11 * 64 * 64;
    unsigned short* wbl2  = wbh2 + NRESU * 11 * 64 * 64;

    hipMemsetAsync(progb, 0, 40 * 32 * sizeof(int), stream);

    k_prepw_mfma<<<528, 256, 0, stream>>>(rw1, wbh1, wbl1);
    k_prepw_mfma<<<528, 256, 0, stream>>>(rw2, wbh2, wbl2);
    k_frontend<<<2048, 256, 0, stream>>>(input, c1w, c1b, c2w, c2b, x0buf);
    for (int uu = 0; uu < NRESU; uu++) {
        k_resconv_mfma<<<1024, 256, 0, stream>>>(x0buf, t1buf, wbh1 + uu * 45056, wbl1 + uu * 45056,
                                                 rb1 + uu * 64, bn1g + uu * 64, bn1b + uu * 64,
                                                 bn1m + uu * 64, bn1v + uu * 64, 0);
        k_resconv_mfma<<<1024, 256, 0, stream>>>(t1buf, x0buf, wbh2 + uu * 45056, wbl2 + uu * 45056,
                                                 rb2 + uu * 64, bn2g + uu * 64, bn2b + uu * 64,
                                                 bn2m + uu * 64, bn2v + uu * 64, 1);
    }
    k_transpose<<<2048, 256, 0, stream>>>(x0buf, Xbf);
    k_lstm<<<80, 512, 0, stream>>>(Xbf, wih, whh, bih, bhh, ringb, fhbuf, progb);
    k_head<<<1, 64, 0, stream>>>(fhbuf, outw, outb, (float*)d_out);
}

// Round 16
// 2660.424 us; speedup vs baseline: 1.3322x; 1.0079x over previous
//
#include <hip/hip_runtime.h>
#include <hip/hip_bf16.h>

#define TL 2048
#define NB 64
#define NH 64
#define NLAY 10
#define NRESU 3
#define RSTEP 64

typedef float f32x4 __attribute__((ext_vector_type(4)));
typedef short bhalf8 __attribute__((ext_vector_type(8)));
typedef short bhalf4 __attribute__((ext_vector_type(4)));

__device__ __forceinline__ unsigned short f2bf(float f) {
    unsigned u = __float_as_uint(f);
    unsigned r = u + 0x7fffu + ((u >> 16) & 1u);
    return (unsigned short)(r >> 16);
}
__device__ __forceinline__ float bf2f(unsigned short h) {
    return __uint_as_float(((unsigned)h) << 16);
}
// raw 2^x / 2^-x (v_exp_f32; neg is a free input modifier)
__device__ __forceinline__ float exp2_pos(float x) {
    float r; asm("v_exp_f32 %0, %1" : "=v"(r) : "v"(x)); return r;
}
__device__ __forceinline__ float exp2_neg(float x) {
    float r; asm("v_exp_f32 %0, -%1" : "=v"(r) : "v"(x)); return r;
}

// ---------------- frontend ----------------
__global__ __launch_bounds__(256) void k_frontend(
    const float* __restrict__ in,
    const float* __restrict__ c1w, const float* __restrict__ c1b,
    const float* __restrict__ c2w, const float* __restrict__ c2b,
    float* __restrict__ x0)
{
    __shared__ float s_c1w[128];
    __shared__ float s_c1b[32];
    __shared__ float s_c2w[64 * 33];
    __shared__ float s_c2b[64];
    __shared__ float h1[64 * 33];
    __shared__ float ot[64 * 65];
    int tid = threadIdx.x;
    int b = blockIdx.x >> 5;
    int l0 = (blockIdx.x & 31) << 6;
    if (tid < 128) s_c1w[tid] = c1w[tid];
    if (tid < 32) s_c1b[tid] = c1b[tid];
    if (tid < 64) s_c2b[tid] = c2b[tid];
    for (int r = tid; r < 2048; r += 256) s_c2w[(r >> 5) * 33 + (r & 31)] = c2w[r];
    __syncthreads();
    if (tid < 64) {
        const float* ip = in + ((size_t)b * TL + l0 + tid) * 4;
        float x0v = ip[0], x1 = ip[1], x2 = ip[2], x3 = ip[3];
#pragma unroll
        for (int o = 0; o < 32; o++) {
            float a = s_c1w[o * 4 + 0] * x0v + s_c1w[o * 4 + 1] * x1 +
                      s_c1w[o * 4 + 2] * x2 + s_c1w[o * 4 + 3] * x3 + s_c1b[o];
            h1[tid * 33 + o] = fmaxf(a, 0.0f);
        }
    }
    __syncthreads();
    {
        int o = tid & 63, lg = tid >> 6;
#pragma unroll
        for (int j = 0; j < 16; j++) {
            int l = lg * 16 + j;
            float a = s_c2b[o];
#pragma unroll
            for (int i = 0; i < 32; i++) a += h1[l * 33 + i] * s_c2w[o * 33 + i];
            ot[o * 65 + l] = fmaxf(a, 0.0f);
        }
    }
    __syncthreads();
    for (int r = 0; r < 16; r++) {
        int idx = tid + 256 * r;
        int c = idx >> 6, l = idx & 63;
        x0[((size_t)b * 64 + c) * TL + l0 + l] = ot[c * 65 + l];
    }
}

// ---------------- weight prep: [u][o][i][k] f32 -> [u][k][o][i] bf16 hi/lo ----------------
__global__ __launch_bounds__(256) void k_prepw_mfma(
    const float* __restrict__ w, unsigned short* __restrict__ wbh, unsigned short* __restrict__ wbl)
{
    int idx = blockIdx.x * 256 + threadIdx.x;
    if (idx >= NRESU * 11 * 64 * 64) return;
    int i = idx & 63;
    int rest = idx >> 6;
    int o = rest & 63;
    rest >>= 6;
    int k = rest % 11;
    int u = rest / 11;
    float v = w[(((size_t)u * 64 + o) * 64 + i) * 11 + k];
    unsigned short hb = f2bf(v);
    float lo = v - bf2f(hb);
    wbh[idx] = hb;
    wbl[idx] = f2bf(lo);
}

// ---------------- residual conv k=11 pad=5 via MFMA (3-term split bf16) ----------------
// XT row stride 76 ushorts (152 B): dword stride 38 = 6 mod 32 -> 16 banks,
// ~2-way on reads / 1.58x on writes (was 36 = 4 mod 32 -> 8 banks, 8-way reads).
// 152 B is 8B-aligned -> A-frags via 2x ds_read_b64 (b128 needs 16B, unreachable
// with a conflict-free stride).
#define XTS 76
__global__ __launch_bounds__(256) void k_resconv_mfma(
    const float* __restrict__ in, float* __restrict__ out,
    const unsigned short* __restrict__ wbh, const unsigned short* __restrict__ wbl,
    const float* __restrict__ bias,
    const float* __restrict__ bg, const float* __restrict__ bb,
    const float* __restrict__ bm, const float* __restrict__ bv,
    int accumulate)
{
    __shared__ float sscale[64], sshift[64];
    __shared__ __align__(16) char smem[43776];
    unsigned short* XTH = (unsigned short*)smem;           // [144][76]
    unsigned short* XTL = XTH + 144 * XTS;                 // [144][76]
    float* Yb = (float*)smem;                              // [128][66] overlay (post-MFMA)

    int tid = threadIdx.x;
    int b = blockIdx.x >> 4;
    int l0 = (blockIdx.x & 15) << 7;
    int lane = tid & 63;
    int wv = tid >> 6;
    int l15 = lane & 15, l4 = lane >> 4;

    if (tid < 64) {
        float sc = bg[tid] * rsqrtf(bv[tid] + 1e-5f);
        sscale[tid] = sc;
        sshift[tid] = bb[tid] - bm[tid] * sc;
    }
    __syncthreads();

    // ---- COALESCED stage: lane = column l (global), rows i ----
    {
        int lcol = tid & 63;
        int ib = tid >> 6;
#pragma unroll
        for (int it = 0; it < 16; it++) {
            int i = ib + it * 4;
            float sc = sscale[i], sh = sshift[i];
            const float* ip = in + ((size_t)b * 64 + i) * TL;
#pragma unroll
            for (int jc = 0; jc < 3; jc++) {
                int ll = jc * 64 + lcol;
                if (ll < 138) {
                    int l = l0 - 5 + ll;
                    float v = 0.0f;
                    if (l >= 0 && l < TL) v = fmaxf(ip[l] * sc + sh, 0.0f);
                    unsigned short hb = f2bf(v);
                    float lo = v - bf2f(hb);
                    XTH[ll * XTS + i] = hb;
                    XTL[ll * XTS + i] = f2bf(lo);
                }
            }
        }
    }
    __syncthreads();

    f32x4 acc[2][4];
#pragma unroll
    for (int s = 0; s < 2; s++)
#pragma unroll
        for (int ot = 0; ot < 4; ot++) acc[s][ot] = (f32x4){0, 0, 0, 0};

    for (int k = 0; k < 11; k++) {
#pragma unroll
        for (int ic = 0; ic < 2; ic++) {
            bhalf8 ah[2], al[2];
#pragma unroll
            for (int s = 0; s < 2; s++) {
                int row = (wv * 2 + s) * 16 + l15 + k;
                int off = row * XTS + ic * 32 + l4 * 8;
                bhalf4 h0 = *(const bhalf4*)&XTH[off];
                bhalf4 h1v = *(const bhalf4*)&XTH[off + 4];
                bhalf4 lo0 = *(const bhalf4*)&XTL[off];
                bhalf4 lo1 = *(const bhalf4*)&XTL[off + 4];
                ah[s] = (bhalf8){h0[0], h0[1], h0[2], h0[3], h1v[0], h1v[1], h1v[2], h1v[3]};
                al[s] = (bhalf8){lo0[0], lo0[1], lo0[2], lo0[3], lo1[0], lo1[1], lo1[2], lo1[3]};
            }
#pragma unroll
            for (int ot = 0; ot < 4; ot++) {
                size_t woff = ((size_t)(k * 64 + ot * 16 + l15)) * 64 + ic * 32 + l4 * 8;
                bhalf8 bh = *(const bhalf8*)&wbh[woff];
                bhalf8 bl = *(const bhalf8*)&wbl[woff];
#pragma unroll
                for (int s = 0; s < 2; s++) {
                    acc[s][ot] = __builtin_amdgcn_mfma_f32_16x16x32_bf16(ah[s], bh, acc[s][ot], 0, 0, 0);
                    acc[s][ot] = __builtin_amdgcn_mfma_f32_16x16x32_bf16(al[s], bh, acc[s][ot], 0, 0, 0);
                    acc[s][ot] = __builtin_amdgcn_mfma_f32_16x16x32_bf16(ah[s], bl, acc[s][ot], 0, 0, 0);
                }
            }
        }
    }
    __syncthreads();

#pragma unroll
    for (int s = 0; s < 2; s++)
#pragma unroll
        for (int ot = 0; ot < 4; ot++)
#pragma unroll
            for (int r = 0; r < 4; r++)
                Yb[((wv * 2 + s) * 16 + l4 * 4 + r) * 66 + ot * 16 + l15] = acc[s][ot][r];
    __syncthreads();

    {
        int o = tid >> 2, ls0 = (tid & 3) * 32;
        float bsv = bias[o];
        float* op = out + ((size_t)b * 64 + o) * TL + l0 + ls0;
        if (accumulate) {
#pragma unroll
            for (int j = 0; j < 32; j++) op[j] += Yb[(ls0 + j) * 66 + o] + bsv;
        } else {
#pragma unroll
            for (int j = 0; j < 32; j++) op[j] = Yb[(ls0 + j) * 66 + o] + bsv;
        }
    }
}

// ---------------- transpose+cast: [NB][64][TL] f32 -> [TL][NB*64] bf16 ----------------
__global__ __launch_bounds__(256) void k_transpose(
    const float* __restrict__ x0, unsigned short* __restrict__ Xbf)
{
    __shared__ float t[64 * 65];
    int tid = threadIdx.x;
    int b = blockIdx.x >> 5;
    int t0 = (blockIdx.x & 31) << 6;
    for (int r = 0; r < 16; r++) {
        int idx = tid + 256 * r;
        int c = idx >> 6, tt = idx & 63;
        t[c * 65 + tt] = x0[((size_t)b * 64 + c) * TL + t0 + tt];
    }
    __syncthreads();
    for (int r = 0; r < 16; r++) {
        int idx = tid + 256 * r;
        int tt = idx >> 6, c = idx & 63;
        Xbf[((size_t)(t0 + tt)) * (NB * NH) + b * 64 + c] = f2bf(t[c * 65 + tt]);
    }
}

// ---------------- pipelined 10-layer LSTM (round-15, passing, unchanged) ----------------
__global__ __launch_bounds__(512) void k_lstm(
    const unsigned short* __restrict__ Xbf,
    const float* __restrict__ w_ih, const float* __restrict__ w_hh,
    const float* __restrict__ b_ih, const float* __restrict__ b_hh,
    unsigned short* __restrict__ ring, float* __restrict__ final_h, int* prog)
{
    int bid = blockIdx.x;             // 0..79; active: bid&7 < 4
    int grp = bid & 7;
    int layer = bid >> 3;
    if (grp >= 4 || layer >= NLAY) return;
    int b0 = grp * 16;
    int tid = threadIdx.x;
    int w = tid >> 6;                 // wave 0..7
    int lane = tid & 63;
    int l15 = lane & 15, l4 = lane >> 4;
    int w4 = w & 3;                   // tile set / u-range
    int rhalf = w >> 2;               // batch half within l4-quad
    int u = w4 * 16 + l15;            // this lane's u
    int self = layer * 4 + grp;
    const bool has_store = (layer < NLAY - 1);
    const bool use_ring = (layer > 0);
    int brow = tid >> 5;              // staging batch row 0..15
    int cc0 = (tid & 31) * 2;         // staging u pair base

    __shared__ __align__(16) unsigned short XH[2][16][136];   // [buf][b][x(0..63)|h(64..127)]

    const float LOG2E = 1.44269504f;

    // ---- weights: 4 gates x 4 kt for u (pre-scaled: i,f,o x log2e ; g x 2log2e) ----
    bhalf8 Bh[4][4];
    float bv[4];
#pragma unroll
    for (int g = 0; g < 4; g++) {
        float wsc = (g == 2) ? 2.0f * LOG2E : LOG2E;
        int n = g * 64 + u;
        const float* rih = w_ih + ((size_t)layer * 256 + n) * 64;
        const float* rhh = w_hh + ((size_t)layer * 256 + n) * 64;
        bv[g] = (b_ih[layer * 256 + n] + b_hh[layer * 256 + n]) * wsc;
#pragma unroll
        for (int kt = 0; kt < 4; kt++) {
#pragma unroll
            for (int j = 0; j < 8; j++) {
                int k = kt * 32 + l4 * 8 + j;
                float v = (k < 64) ? rih[k] : rhh[k - 64];
                Bh[g][kt][j] = (short)f2bf(v * wsc);
            }
        }
    }
    for (int idx = tid; idx < 2 * 16 * 64; idx += 512) {
        XH[idx >> 10][(idx >> 6) & 15][64 + (idx & 63)] = 0;
    }
    float cst[2] = {0.f, 0.f};

    int* p_self = prog + self * 32;
    int* p_prev = prog + (self - 4) * 32;
    int* p_next = prog + (self + 4) * 32;
    int cached_prev = 0, cached_next = 0;

#define POLL_GE(ptr, tgt, cachev)                                                     \
    if (cachev < (tgt)) {                                                             \
        int v_; long g_ = 0;                                                          \
        while ((v_ = __hip_atomic_load(ptr, __ATOMIC_ACQUIRE,                         \
                        __HIP_MEMORY_SCOPE_AGENT)) < (tgt) && ++g_ < 1500000)         \
            __builtin_amdgcn_s_sleep(2);                                              \
        cachev = v_;                                                                  \
    }

    // ---- prologue ----
    if (tid == 0 && layer > 0) { POLL_GE(p_prev, 32, cached_prev); }
    __syncthreads();
    unsigned px[4];
    {
        unsigned p0;
        if (!use_ring) {
            const unsigned short* s0 = Xbf + (size_t)(b0 + brow) * 64 + cc0;
            asm volatile("global_load_dword %0, %1, off" : "=&v"(p0) : "v"(s0) : "memory");
        } else {
            const unsigned short* s0 = ring + ((size_t)(layer - 1) * RSTEP) * 4096 + (b0 + brow) * 64 + cc0;
            asm volatile("global_load_dword %0, %1, off sc0 sc1" : "=&v"(p0) : "v"(s0) : "memory");
        }
        asm volatile("s_waitcnt vmcnt(0)" ::: "memory");
        __builtin_amdgcn_sched_barrier(0);
        *(unsigned*)&XH[0][brow][cc0] = p0;
#pragma unroll
        for (int pre = 1; pre <= 3; pre++) {
            if (!use_ring) {
                const unsigned short* sp = Xbf + ((size_t)pre * NB + b0 + brow) * 64 + cc0;
                asm volatile("global_load_dword %0, %1, off" : "=&v"(px[pre]) : "v"(sp) : "memory");
            } else {
                const unsigned short* sp = ring + ((size_t)(layer - 1) * RSTEP + pre) * 4096 + (b0 + brow) * 64 + cc0;
                asm volatile("global_load_dword %0, %1, off sc0 sc1" : "=&v"(px[pre]) : "v"(sp) : "memory");
            }
        }
    }
    asm volatile("s_waitcnt vmcnt(0)" ::: "memory");
    __builtin_amdgcn_sched_barrier(0);
    __syncthreads();

    for (int t0 = 0; t0 < TL; t0 += 8) {
#pragma unroll
        for (int ts = 0; ts < 8; ++ts) {
            const int p = ts & 1, q = p ^ 1;
            const int t = t0 + ts;
            const int cons = (ts + 1) & 3;   // px slot holding x(t+1)
            const int pref = ts & 3;         // slot to refill with x(t+4)

            // ---- gates for u (all 4), bias in init ----
            f32x4 acc[4];
#pragma unroll
            for (int g = 0; g < 4; g++) acc[g] = (f32x4){bv[g], bv[g], bv[g], bv[g]};
#pragma unroll
            for (int kt = 0; kt < 4; kt++) {
                bhalf8 Ah = *(const bhalf8*)&XH[p][l15][kt * 32 + l4 * 8];
                acc[0] = __builtin_amdgcn_mfma_f32_16x16x32_bf16(Ah, Bh[0][kt], acc[0], 0, 0, 0);
                acc[1] = __builtin_amdgcn_mfma_f32_16x16x32_bf16(Ah, Bh[1][kt], acc[1], 0, 0, 0);
                acc[2] = __builtin_amdgcn_mfma_f32_16x16x32_bf16(Ah, Bh[2][kt], acc[2], 0, 0, 0);
                acc[3] = __builtin_amdgcn_mfma_f32_16x16x32_bf16(Ah, Bh[3][kt], acc[3], 0, 0, 0);
            }

            // ---- nonlinearity (exp2-native, accs pre-scaled) ----
            float hv[2];
#pragma unroll
            for (int rr = 0; rr < 2; rr++) {
                int r = rhalf * 2 + rr;
                float si = __builtin_amdgcn_rcpf(1.0f + exp2_neg(acc[0][r]));
                float sf = __builtin_amdgcn_rcpf(1.0f + exp2_neg(acc[1][r]));
                float tg = 1.0f - 2.0f * __builtin_amdgcn_rcpf(exp2_pos(acc[2][r]) + 1.0f);
                float c = sf * cst[rr] + si * tg;
                cst[rr] = c;
                float tc = 1.0f - 2.0f * __builtin_amdgcn_rcpf(exp2_pos(c * (2.0f * LOG2E)) + 1.0f);
                float so = __builtin_amdgcn_rcpf(1.0f + exp2_neg(acc[3][r]));
                hv[rr] = so * tc;
            }
            unsigned hpk;
            asm("v_cvt_pk_bf16_f32 %0, %1, %2" : "=v"(hpk) : "v"(hv[0]), "v"(hv[1]));
            unsigned hb0 = hpk & 0xffffu;
            unsigned hb1 = hpk >> 16;

            // ---- counted wait for x(t+1) (loaded 3 steps ago) ----
            if (has_store) { asm volatile("s_waitcnt vmcnt(6)" ::: "memory"); }
            else           { asm volatile("s_waitcnt vmcnt(2)" ::: "memory"); }
            __builtin_amdgcn_sched_barrier(0);

            // ---- stage x(t+1) into buf q ----
            *(unsigned*)&XH[q][brow][cc0] = px[cons];

            // ---- own h into buf q + ring ----
            {
                int bb = l4 * 4 + rhalf * 2;
                XH[q][bb][64 + u] = (unsigned short)hb0;
                XH[q][bb + 1][64 + u] = (unsigned short)hb1;
                if (has_store) {
                    unsigned short* ap0 = ring + ((size_t)layer * RSTEP + (t & 63)) * 4096 + (b0 + bb) * 64 + u;
                    asm volatile("global_store_short %0, %1, off sc0 sc1" :: "v"(ap0), "v"(hb0) : "memory");
                    asm volatile("global_store_short %0, %1, off sc0 sc1" :: "v"(ap0 + 64), "v"(hb1) : "memory");
                } else if (t == TL - 1) {
                    final_h[(b0 + bb) * NH + u] = hv[0];
                    final_h[(b0 + bb + 1) * NH + u] = hv[1];
                }
            }

            // ---- prefetch x(t+4) ----
            {
                int tt = t + 4; if (tt > TL - 1) tt = TL - 1;
                if (!use_ring) {
                    const unsigned short* sp = Xbf + ((size_t)tt * NB + b0 + brow) * 64 + cc0;
                    asm volatile("global_load_dword %0, %1, off" : "=&v"(px[pref]) : "v"(sp) : "memory");
                } else {
                    const unsigned short* sp = ring + ((size_t)(layer - 1) * RSTEP + (tt & 63)) * 4096 + (b0 + brow) * 64 + cc0;
                    asm volatile("global_load_dword %0, %1, off sc0 sc1" : "=&v"(px[pref]) : "v"(sp) : "memory");
                }
            }

            asm volatile("s_waitcnt lgkmcnt(0)" ::: "memory");
            __builtin_amdgcn_s_barrier();
            __builtin_amdgcn_sched_barrier(0);
        }

        // ---- superstep end: drain stores (vmcnt(1)), publish, slacked polls ----
        if (has_store) { asm volatile("s_waitcnt vmcnt(1)" ::: "memory"); }
        __builtin_amdgcn_s_barrier();
        __builtin_amdgcn_sched_barrier(0);
        if (tid == 0) {
            __hip_atomic_store(p_self, t0, __ATOMIC_RELEASE, __HIP_MEMORY_SCOPE_AGENT);
            int nt0 = t0 + 8;
            if (nt0 < TL) {
                if (use_ring) {
                    int tgt = nt0 + 16; if (tgt > TL) tgt = TL;
                    POLL_GE(p_prev, tgt, cached_prev);
                }
                if (has_store) {
                    int need = nt0 - 64;
                    if (need > 0) { POLL_GE(p_next, need, cached_next); }
                }
            }
        }
        __builtin_amdgcn_s_barrier();
        __builtin_amdgcn_sched_barrier(0);
    }

    // ---- epilogue ----
    asm volatile("s_waitcnt vmcnt(0)" ::: "memory");
    __builtin_amdgcn_s_barrier();
    if (tid == 0) {
        __hip_atomic_store(p_self, TL, __ATOMIC_RELEASE, __HIP_MEMORY_SCOPE_AGENT);
    }
#undef POLL_GE
}

// ---------------- head ----------------
__global__ void k_head(const float* __restrict__ fh, const float* __restrict__ ow,
                       const float* __restrict__ ob, float* __restrict__ out)
{
    int b = threadIdx.x;
    if (b >= NB) return;
    const float* h = fh + b * NH;
    float l0 = ob[0], l1 = ob[1];
    for (int uu = 0; uu < 64; uu++) { l0 += h[uu] * ow[uu * 2]; l1 += h[uu] * ow[uu * 2 + 1]; }
    float m = fmaxf(l0, l1);
    float s = expf(l0 - m) + expf(l1 - m);
    float ls = m + logf(s);
    out[b * 2] = l0 - ls;
    out[b * 2 + 1] = l1 - ls;
}

extern "C" void kernel_launch(void* const* d_in, const int* in_sizes, int n_in,
                              void* d_out, int out_size, void* d_ws, size_t ws_size,
                              hipStream_t stream) {
    const float* input = (const float*)d_in[0];
    const float* c1w = (const float*)d_in[2];
    const float* c1b = (const float*)d_in[3];
    const float* c2w = (const float*)d_in[4];
    const float* c2b = (const float*)d_in[5];
    const float* bn1g = (const float*)d_in[6];
    const float* bn1b = (const float*)d_in[7];
    const float* bn1m = (const float*)d_in[8];
    const float* bn1v = (const float*)d_in[9];
    const float* rw1 = (const float*)d_in[10];
    const float* rb1 = (const float*)d_in[11];
    const float* bn2g = (const float*)d_in[12];
    const float* bn2b = (const float*)d_in[13];
    const float* bn2m = (const float*)d_in[14];
    const float* bn2v = (const float*)d_in[15];
    const float* rw2 = (const float*)d_in[16];
    const float* rb2 = (const float*)d_in[17];
    const float* wih = (const float*)d_in[18];
    const float* whh = (const float*)d_in[19];
    const float* bih = (const float*)d_in[20];
    const float* bhh = (const float*)d_in[21];
    const float* outw = (const float*)d_in[22];
    const float* outb = (const float*)d_in[23];

    float* ws = (float*)d_ws;
    float*          x0buf = ws;                              // [NB][64][TL] f32
    float*          t1buf = x0buf + 8388608;                 // [NB][64][TL] f32
    unsigned short* Xbf   = (unsigned short*)(t1buf + 8388608);  // [TL][NB*64] bf16
    unsigned short* ringb = Xbf + 8388608;                   // [9][64][64b][64u] bf16
    float*          fhbuf = (float*)(ringb + 2359296);       // [NB][NH]
    int*            progb = (int*)(fhbuf + 4096);            // 40 flags x 32
    unsigned short* wbh1  = (unsigned short*)(progb + 40 * 32);   // [3][11][64][64]
    unsigned short* wbl1  = wbh1 + NRESU * 11 * 64 * 64;
    unsigned short* wbh2  = wbl1 + NRESU * 11 * 64 * 64;
    unsigned short* wbl2  = wbh2 + NRESU * 11 * 64 * 64;

    hipMemsetAsync(progb, 0, 40 * 32 * sizeof(int), stream);

    k_prepw_mfma<<<528, 256, 0, stream>>>(rw1, wbh1, wbl1);
    k_prepw_mfma<<<528, 256, 0, stream>>>(rw2, wbh2, wbl2);
    k_frontend<<<2048, 256, 0, stream>>>(input, c1w, c1b, c2w, c2b, x0buf);
    for (int uu = 0; uu < NRESU; uu++) {
        k_resconv_mfma<<<1024, 256, 0, stream>>>(x0buf, t1buf, wbh1 + uu * 45056, wbl1 + uu * 45056,
                                                 rb1 + uu * 64, bn1g + uu * 64, bn1b + uu * 64,
                                                 bn1m + uu * 64, bn1v + uu * 64, 0);
        k_resconv_mfma<<<1024, 256, 0, stream>>>(t1buf, x0buf, wbh2 + uu * 45056, wbl2 + uu * 45056,
                                                 rb2 + uu * 64, bn2g + uu * 64, bn2b + uu * 64,
                                                 bn2m + uu * 64, bn2v + uu * 64, 1);
    }
    k_transpose<<<2048, 256, 0, stream>>>(x0buf, Xbf);
    k_lstm<<<80, 512, 0, stream>>>(Xbf, wih, whh, bih, bhh, ringb, fhbuf, progb);
    k_head<<<1, 64, 0, stream>>>(fhbuf, outw, outb, (float*)d_out);
}